// Round 2
// baseline (1273.426 us; speedup 1.0000x reference)
//
#include <hip/hip_runtime.h>
#include <math.h>

// Problem constants
#define BSZ   4
#define TT    256
#define NN    32
#define DM    128
#define LL    2
#define SS    16
#define DCV   4
#define DI    256
#define DTR   8
#define KK    4
#define RR    16
#define BN_   128          // BSZ*NN
#define TOK   32768        // BN_*TT

__device__ __forceinline__ float sigm(float x) { return 1.f / (1.f + expf(-x)); }

// ---------------------------------------------------------------------------
// pack x (B,T,N,D) -> h (BN,T,D)
__global__ __launch_bounds__(128) void pack_h_k(const float* __restrict__ x, float* __restrict__ h)
{
    int d = threadIdx.x;
    int tok = blockIdx.x;
    int t = tok & 255;
    int bn = tok >> 8;
    int b = bn >> 5, n = bn & 31;
    h[(size_t)tok * DM + d] = x[(((size_t)b * TT + t) * NN + n) * DM + d];
}

// ---------------------------------------------------------------------------
// Generic fp32 tiled GEMM: C[M,N] = A[M,K] @ W[N,K]^T (+epilogue)
// EPI: 0 none, 4 accumulate into C, 5 +bias then gelu(c<256)/tanh(c>=256),
//      6 scale by aux[row*4 + (col>>4)]
template<int BM, int BN, int TM, int TN, int EPI>
__global__ __launch_bounds__(256)
void gemm_k(const float* __restrict__ A, int lda,
            const float* __restrict__ W,
            const float* __restrict__ bias,
            float* C, int ldc,
            int M, int N, int K,
            const float* __restrict__ aux)
{
    constexpr int BK = 16;
    constexpr int LDS_A = BM + 4;
    constexpr int LDS_B = BN + 4;
    static_assert((BM / TM) * (BN / TN) == 256, "256 threads");
    constexpr int NA = BM * BK / 1024;   // float4 loads per thread for A
    constexpr int NB = BN * BK / 1024;

    __shared__ float As[BK][LDS_A];
    __shared__ float Ws[BK][LDS_B];

    const int tid = threadIdx.x;
    constexpr int nx = BN / TN;
    const int tx = tid % nx, ty = tid / nx;
    const long row0 = (long)blockIdx.y * BM;
    const long col0 = (long)blockIdx.x * BN;

    float acc[TM][TN];
#pragma unroll
    for (int i = 0; i < TM; i++)
#pragma unroll
        for (int j = 0; j < TN; j++) acc[i][j] = 0.f;

    for (int kk = 0; kk < K; kk += BK) {
        float4 a_reg[NA], w_reg[NB];
#pragma unroll
        for (int i = 0; i < NA; ++i) {
            int idx = i * 1024 + tid * 4;
            int r = idx >> 4, k0 = idx & 15;
            int k = kk + k0;
            const float* p = A + (row0 + r) * (long)lda + k;
            a_reg[i] = *(const float4*)p;       // K always multiple of 16 here
        }
#pragma unroll
        for (int i = 0; i < NB; ++i) {
            int idx = i * 1024 + tid * 4;
            int r = idx >> 4, k0 = idx & 15;
            long gc = col0 + r;
            int k = kk + k0;
            if (gc < N) {
                const float* p = W + gc * (long)K + k;
                w_reg[i] = *(const float4*)p;
            } else w_reg[i] = make_float4(0.f, 0.f, 0.f, 0.f);
        }
        __syncthreads();
#pragma unroll
        for (int i = 0; i < NA; ++i) {
            int idx = i * 1024 + tid * 4;
            int r = idx >> 4, k0 = idx & 15;
            As[k0 + 0][r] = a_reg[i].x; As[k0 + 1][r] = a_reg[i].y;
            As[k0 + 2][r] = a_reg[i].z; As[k0 + 3][r] = a_reg[i].w;
        }
#pragma unroll
        for (int i = 0; i < NB; ++i) {
            int idx = i * 1024 + tid * 4;
            int r = idx >> 4, k0 = idx & 15;
            Ws[k0 + 0][r] = w_reg[i].x; Ws[k0 + 1][r] = w_reg[i].y;
            Ws[k0 + 2][r] = w_reg[i].z; Ws[k0 + 3][r] = w_reg[i].w;
        }
        __syncthreads();
#pragma unroll
        for (int k = 0; k < BK; ++k) {
            float a_f[TM], w_f[TN];
#pragma unroll
            for (int i = 0; i < TM; i += 4)
                *(float4*)&a_f[i] = *(const float4*)&As[k][ty * TM + i];
#pragma unroll
            for (int j = 0; j < TN; j += 4)
                *(float4*)&w_f[j] = *(const float4*)&Ws[k][tx * TN + j];
#pragma unroll
            for (int i = 0; i < TM; i++)
#pragma unroll
                for (int j = 0; j < TN; j++)
                    acc[i][j] = fmaf(a_f[i], w_f[j], acc[i][j]);
        }
    }
    // epilogue
#pragma unroll
    for (int i = 0; i < TM; i++) {
        long r = row0 + ty * TM + i;
#pragma unroll
        for (int j = 0; j < TN; j++) {
            long c = col0 + tx * TN + j;
            if (c < N) {
                float v = acc[i][j];
                if (EPI == 5) {
                    v += bias[c];
                    if (c < 256) v = 0.5f * v * (1.f + erff(v * 0.70710678118654752f));
                    else         v = tanhf(v);
                } else if (EPI == 6) { v *= aux[r * 4 + (c >> 4)]; }
                if (EPI == 4) C[r * ldc + c] += v;
                else          C[r * ldc + c] = v;
            }
        }
    }
}

// ---------------------------------------------------------------------------
// causal depthwise conv (DC=4) + SiLU; reads xh-half of xz, writes xh
__global__ __launch_bounds__(256) void conv_silu_k(const float* __restrict__ xz,
                                                   const float* __restrict__ cw,
                                                   const float* __restrict__ cb,
                                                   float* __restrict__ xh)
{
    int c = threadIdx.x;       // 0..255
    int t = blockIdx.x;        // 0..255
    int bn = blockIdx.y;       // 0..127
    float w0 = cw[c * 4 + 0], w1 = cw[c * 4 + 1], w2 = cw[c * 4 + 2], w3 = cw[c * 4 + 3];
    size_t base = ((size_t)bn * TT + t) * 512 + c;
    float acc = cb[c] + w3 * xz[base];
    if (t >= 1) acc += w2 * xz[base - 512];
    if (t >= 2) acc += w1 * xz[base - 1024];
    if (t >= 3) acc += w0 * xz[base - 1536];
    xh[((size_t)bn * TT + t) * DI + c] = acc * sigm(acc);
}

// ---------------------------------------------------------------------------
// dt = softplus(xdbl[:, :8] @ dtw^T + dtb), written into xz[:, 0:256] (stride 512)
__global__ __launch_bounds__(256) void dt_k(const float* __restrict__ xdbl,
                                            const float* __restrict__ dtw,
                                            const float* __restrict__ dtb,
                                            float* __restrict__ dtout)
{
    int n = threadIdx.x;       // 0..255
    int tok = blockIdx.x;
    const float* xr = xdbl + (size_t)tok * 40;
    float acc = dtb[n];
#pragma unroll
    for (int k = 0; k < 8; k++) acc = fmaf(xr[k], dtw[n * 8 + k], acc);
    float sp = (acc > 20.f) ? acc : log1pf(expf(acc));
    dtout[(size_t)tok * 512 + n] = sp;
}

// ---------------------------------------------------------------------------
// selective scan fused with +D*x and *silu(z). One thread per (bn,d,s).
// dt lives in xz[:,0:256]; z in xz[:,256:512]. yg written in-place over xh.
__global__ __launch_bounds__(256) void scan_k(const float* __restrict__ xz,
                                              const float* xh,          // no restrict: aliases yg
                                              const float* __restrict__ xdbl,
                                              const float* __restrict__ A_log,
                                              const float* __restrict__ Dp,
                                              float* yg)
{
    int l = threadIdx.x;
    int g = l >> 4, s = l & 15;
    int bn = blockIdx.x >> 4;
    int d = ((blockIdx.x & 15) << 4) + g;
    float Av = -expf(A_log[d * SS + s]);
    float Dv = Dp[d];
    float state = 0.f;
    size_t tok = (size_t)bn * TT;
    for (int t = 0; t < TT; ++t, ++tok) {
        float a  = xz[tok * 512 + d];          // dt
        float xv = xh[tok * DI + d];
        float Bv = xdbl[tok * 40 + 8 + s];
        float Cv = xdbl[tok * 40 + 24 + s];
        state = expf(a * Av) * state + (a * Bv) * xv;
        float y = state * Cv;
        y += __shfl_xor(y, 1, 64);
        y += __shfl_xor(y, 2, 64);
        y += __shfl_xor(y, 4, 64);
        y += __shfl_xor(y, 8, 64);
        if (s == 0) {
            float z = xz[tok * 512 + 256 + d];
            yg[tok * DI + d] = (y + Dv * xv) * (z * sigm(z));
        }
    }
}

// ---------------------------------------------------------------------------
// per-token small projections on fused buffer (stride 512):
// cols 0..127 = gelu(gate1), 128..255 = gelu(mix1)
__global__ __launch_bounds__(64) void gate_k(const float* __restrict__ gmb,
                                             const float* __restrict__ gw2,
                                             const float* __restrict__ gb2,
                                             const float* __restrict__ mw2,
                                             const float* __restrict__ mb2,
                                             const float* __restrict__ Ascale,
                                             float* __restrict__ ws4,
                                             float* __restrict__ dts,
                                             float* __restrict__ gs)
{
    int l = threadIdx.x;       // 0..63
    int tok = blockIdx.x;
    const float* g1 = gmb + (size_t)tok * 512;
    float a0 = g1[l], a1 = g1[l + 64];
    float m0 = g1[128 + l], m1v = g1[192 + l];
    float p[5];
#pragma unroll
    for (int j = 0; j < 5; j++)
        p[j] = a0 * gw2[j * DM + l] + a1 * gw2[j * DM + l + 64];
    float q = m0 * mw2[l] + m1v * mw2[l + 64];
#pragma unroll
    for (int off = 32; off; off >>= 1) {
#pragma unroll
        for (int j = 0; j < 5; j++) p[j] += __shfl_xor(p[j], off, 64);
        q += __shfl_xor(q, off, 64);
    }
    if (l == 0) {
        float go[5];
#pragma unroll
        for (int j = 0; j < 5; j++) go[j] = p[j] + gb2[j];
        float mx = fmaxf(fmaxf(go[0], go[1]), fmaxf(go[2], go[3]));
        float e[4], sum = 0.f;
#pragma unroll
        for (int k = 0; k < 4; k++) { e[k] = expf(go[k] - mx); sum += e[k]; }
        float inv = 1.f / sum;
#pragma unroll
        for (int k = 0; k < 4; k++) ws4[(size_t)tok * 4 + k] = e[k] * inv * Ascale[k];
        dts[tok] = 0.2f * sigm(go[4]);
        gs[tok]  = sigm(q + mb2[0]);
    }
}

// ---------------------------------------------------------------------------
// pack Wu[kr][d] = U[k][d][r], Wv[d][kr] = V[k][r][d]  (both 8192 elems)
__global__ __launch_bounds__(256) void pack_uv_k(const float* __restrict__ U,
                                                 const float* __restrict__ V,
                                                 float* __restrict__ Wu,
                                                 float* __restrict__ Wv)
{
    int i = blockIdx.x * 256 + threadIdx.x;
    if (i < 8192) {
        int kr = i >> 7, d = i & 127;
        int k = kr >> 4, r = kr & 15;
        Wu[i] = U[((size_t)k * DM + d) * RR + r];
        int d2 = i >> 6, kr2 = i & 63;
        int k2 = kr2 >> 4, r2 = kr2 & 15;
        Wv[i] = V[((size_t)k2 * RR + r2) * DM + d2];
    }
}

// ---------------------------------------------------------------------------
// pack Wcat (512x128) = [gw1; mw1; fgw; fbw], bcat(512) = [gb1; mb1; fgb; fbb]
__global__ __launch_bounds__(256) void pack_cat_k(const float* __restrict__ gw1,
                                                  const float* __restrict__ gb1,
                                                  const float* __restrict__ mw1,
                                                  const float* __restrict__ mb1,
                                                  const float* __restrict__ fgw,
                                                  const float* __restrict__ fgb,
                                                  const float* __restrict__ fbw,
                                                  const float* __restrict__ fbb,
                                                  float* __restrict__ Wcat,
                                                  float* __restrict__ bcat)
{
    int i = blockIdx.x * 256 + threadIdx.x;
    if (i < 65536) {
        int r = i >> 7, k = i & 127;
        int sel = r >> 7;         // r/128
        int rr = r & 127;
        const float* src = (sel == 0) ? gw1 : (sel == 1) ? mw1 : (sel == 2) ? fgw : fbw;
        Wcat[i] = src[rr * DM + k];
    }
    if (i < 512) {
        int sel = i >> 7, rr = i & 127;
        const float* src = (sel == 0) ? gb1 : (sel == 1) ? mb1 : (sel == 2) ? fgb : fbb;
        bcat[i] = src[rr];
    }
}

// ---------------------------------------------------------------------------
// final combine + transpose back to (B,T,N,D); gamma/beta live in gmb cols 256..511
__global__ __launch_bounds__(128) void combine_k(const float* __restrict__ h,
                                                 const float* __restrict__ hA,
                                                 const float* __restrict__ hA2,
                                                 const float* __restrict__ gmb,
                                                 const float* __restrict__ dts,
                                                 const float* __restrict__ gs,
                                                 float* __restrict__ out)
{
    int d = threadIdx.x;
    int tok = blockIdx.x;
    int t = tok & 255;
    int bn = tok >> 8;
    int b = bn >> 5, n = bn & 31;
    float dtv = dts[tok], gv = gs[tok];
    size_t i = (size_t)tok * DM + d;
    float u = tanhf(dtv * hA[i] + 0.5f * dtv * dtv * hA2[i]);
    float gamma = gmb[(size_t)tok * 512 + 256 + d];
    float beta  = gmb[(size_t)tok * 512 + 384 + d];
    u = gamma * u + beta;
    out[(((size_t)b * TT + t) * NN + n) * DM + d] = h[i] + gv * u;
}

// ---------------------------------------------------------------------------
extern "C" void kernel_launch(void* const* d_in, const int* in_sizes, int n_in,
                              void* d_out, int out_size, void* d_ws, size_t ws_size,
                              hipStream_t stream)
{
    const float* x       = (const float*)d_in[0];
    const float* in_w    = (const float*)d_in[1];   // (2,512,128)
    const float* conv_w  = (const float*)d_in[2];   // (2,256,4)
    const float* conv_b  = (const float*)d_in[3];   // (2,256)
    const float* xpw     = (const float*)d_in[4];   // (2,40,256)
    const float* dtw     = (const float*)d_in[5];   // (2,256,8)
    const float* dtb     = (const float*)d_in[6];   // (2,256)
    const float* A_log   = (const float*)d_in[7];   // (2,256,16)
    const float* D_skip  = (const float*)d_in[8];   // (2,256)
    const float* ow      = (const float*)d_in[9];   // (2,128,256)
    const float* U       = (const float*)d_in[10];  // (4,128,16)
    const float* V       = (const float*)d_in[11];  // (4,16,128)
    const float* Ascale  = (const float*)d_in[12];  // (4)
    const float* gw1     = (const float*)d_in[13];
    const float* gb1     = (const float*)d_in[14];
    const float* gw2     = (const float*)d_in[15];
    const float* gb2     = (const float*)d_in[16];
    const float* fgw     = (const float*)d_in[17];
    const float* fgb     = (const float*)d_in[18];
    const float* fbw     = (const float*)d_in[19];
    const float* fbb     = (const float*)d_in[20];
    const float* mw1     = (const float*)d_in[21];
    const float* mb1     = (const float*)d_in[22];
    const float* mw2     = (const float*)d_in[23];
    const float* mb2     = (const float*)d_in[24];

    float* ws = (float*)d_ws;
    float* h    = ws;                       //  4,194,304 floats
    float* xz   = h + 4194304;              // 16,777,216 (dt overlays cols 0..255; final: gmb)
    float* xh   = xz + 16777216;            //  8,388,608 (final: hA, hA2)
    float* xdbl = xh + 8388608;             //  1,310,720 (final: Wcat/bcat/Wu/Wv/ws4/dts/gs)
    // total 30,670,848 floats = 122.7 MB

    pack_h_k<<<TOK, 128, 0, stream>>>(x, h);

    for (int l = 0; l < LL; ++l) {
        const float* iw = in_w + (size_t)l * 512 * 128;
        gemm_k<128,128,8,8,0><<<dim3(4,256), 256, 0, stream>>>(
            h, DM, iw, nullptr, xz, 512, TOK, 512, 128, nullptr);
        conv_silu_k<<<dim3(TT, BN_), 256, 0, stream>>>(
            xz, conv_w + (size_t)l * DI * DCV, conv_b + (size_t)l * DI, xh);
        gemm_k<64,64,4,4,0><<<dim3(1,512), 256, 0, stream>>>(
            xh, DI, xpw + (size_t)l * 40 * DI, nullptr, xdbl, 40, TOK, 40, DI, nullptr);
        dt_k<<<TOK, 256, 0, stream>>>(
            xdbl, dtw + (size_t)l * DI * DTR, dtb + (size_t)l * DI, xz);
        scan_k<<<2048, 256, 0, stream>>>(
            xz, xh, xdbl, A_log + (size_t)l * DI * SS, D_skip + (size_t)l * DI, xh);
        gemm_k<128,128,8,8,4><<<dim3(1,256), 256, 0, stream>>>(
            xh, DI, ow + (size_t)l * DM * DI, nullptr, h, DM, TOK, DM, DI, nullptr);
    }

    // ---------------- final stage ----------------
    // gmb = xz (TOK x 512): cols 0..127 gate1(gelu), 128..255 mix1(gelu),
    //                       256..383 gamma(tanh),   384..511 beta(tanh)
    // Z reuses gmb cols 0..63 (ldc=512) after gate_k consumed gate1/mix1.
    float* gmb  = xz;
    float* Zb   = xz;                       // cols 0..63, stride 512
    float* hA   = xh;                       // TOK*128
    float* hA2  = xh + 4194304;             // TOK*128
    float* Wcat = xdbl;                     // 65,536
    float* bcat = xdbl + 65536;             // 512
    float* Wu   = xdbl + 66048;             // 8,192
    float* Wv   = xdbl + 74240;             // 8,192
    float* ws4  = xdbl + 82432;             // TOK*4 = 131,072
    float* dts  = xdbl + 213504;            // TOK
    float* gs   = xdbl + 246272;            // TOK (ends 279,040 < 1,310,720)

    pack_cat_k<<<256, 256, 0, stream>>>(gw1, gb1, mw1, mb1, fgw, fgb, fbw, fbb, Wcat, bcat);
    gemm_k<128,128,8,8,5><<<dim3(4,256), 256, 0, stream>>>(
        h, DM, Wcat, bcat, gmb, 512, TOK, 512, DM, nullptr);
    gate_k<<<TOK, 64, 0, stream>>>(gmb, gw2, gb2, mw2, mb2, Ascale, ws4, dts, gs);
    pack_uv_k<<<32, 256, 0, stream>>>(U, V, Wu, Wv);

    // amix pass 1: Z = (h @ Wu^T) * w   ;  hA = Z @ Wv^T
    gemm_k<64,64,4,4,6><<<dim3(1,512), 256, 0, stream>>>(
        h, DM, Wu, nullptr, Zb, 512, TOK, 64, DM, ws4);
    gemm_k<64,64,4,4,0><<<dim3(2,512), 256, 0, stream>>>(
        Zb, 512, Wv, nullptr, hA, DM, TOK, DM, 64, nullptr);
    // amix pass 2 on hA
    gemm_k<64,64,4,4,6><<<dim3(1,512), 256, 0, stream>>>(
        hA, DM, Wu, nullptr, Zb, 512, TOK, 64, DM, ws4);
    gemm_k<64,64,4,4,0><<<dim3(2,512), 256, 0, stream>>>(
        Zb, 512, Wv, nullptr, hA2, DM, TOK, DM, 64, nullptr);

    combine_k<<<TOK, 128, 0, stream>>>(h, hA, hA2, gmb, dts, gs, (float*)d_out);
}

// Round 3
// 934.227 us; speedup vs baseline: 1.3631x; 1.3631x over previous
//
#include <hip/hip_runtime.h>
#include <math.h>

// Problem constants
#define BSZ   4
#define TT    256
#define NN    32
#define DM    128
#define LL    2
#define SS    16
#define DCV   4
#define DI    256
#define DTR   8
#define KK    4
#define RR    16
#define BN_   128          // BSZ*NN
#define TOK   32768        // BN_*TT

__device__ __forceinline__ float sigm(float x) { return __fdividef(1.f, 1.f + __expf(-x)); }

// ---------------------------------------------------------------------------
// pack x (B,T,N,D) -> h (BN,T,D)
__global__ __launch_bounds__(128) void pack_h_k(const float* __restrict__ x, float* __restrict__ h)
{
    int d = threadIdx.x;
    int tok = blockIdx.x;
    int t = tok & 255;
    int bn = tok >> 8;
    int b = bn >> 5, n = bn & 31;
    h[(size_t)tok * DM + d] = x[(((size_t)b * TT + t) * NN + n) * DM + d];
}

// ---------------------------------------------------------------------------
// Generic fp32 tiled GEMM: C[M,N] = A[M,K] @ W[N,K]^T (+epilogue)
// EPI: 0 none, 4 accumulate into C, 5 +bias then gelu(c<256)/tanh(c>=256),
//      6 scale by aux[row*4 + (col>>4)]
template<int BM, int BN, int TM, int TN, int EPI>
__global__ __launch_bounds__(256)
void gemm_k(const float* __restrict__ A, int lda,
            const float* __restrict__ W,
            const float* __restrict__ bias,
            float* C, int ldc,
            int M, int N, int K,
            const float* __restrict__ aux)
{
    constexpr int BK = 16;
    constexpr int LDS_A = BM + 4;
    constexpr int LDS_B = BN + 4;
    static_assert((BM / TM) * (BN / TN) == 256, "256 threads");
    constexpr int NA = BM * BK / 1024;   // float4 loads per thread for A
    constexpr int NB = BN * BK / 1024;

    __shared__ float As[BK][LDS_A];
    __shared__ float Ws[BK][LDS_B];

    const int tid = threadIdx.x;
    constexpr int nx = BN / TN;
    const int tx = tid % nx, ty = tid / nx;
    const long row0 = (long)blockIdx.y * BM;
    const long col0 = (long)blockIdx.x * BN;

    float acc[TM][TN];
#pragma unroll
    for (int i = 0; i < TM; i++)
#pragma unroll
        for (int j = 0; j < TN; j++) acc[i][j] = 0.f;

    for (int kk = 0; kk < K; kk += BK) {
        float4 a_reg[NA], w_reg[NB];
#pragma unroll
        for (int i = 0; i < NA; ++i) {
            int idx = i * 1024 + tid * 4;
            int r = idx >> 4, k0 = idx & 15;
            int k = kk + k0;
            const float* p = A + (row0 + r) * (long)lda + k;
            a_reg[i] = *(const float4*)p;       // K always multiple of 16 here
        }
#pragma unroll
        for (int i = 0; i < NB; ++i) {
            int idx = i * 1024 + tid * 4;
            int r = idx >> 4, k0 = idx & 15;
            long gc = col0 + r;
            int k = kk + k0;
            if (gc < N) {
                const float* p = W + gc * (long)K + k;
                w_reg[i] = *(const float4*)p;
            } else w_reg[i] = make_float4(0.f, 0.f, 0.f, 0.f);
        }
        __syncthreads();
#pragma unroll
        for (int i = 0; i < NA; ++i) {
            int idx = i * 1024 + tid * 4;
            int r = idx >> 4, k0 = idx & 15;
            As[k0 + 0][r] = a_reg[i].x; As[k0 + 1][r] = a_reg[i].y;
            As[k0 + 2][r] = a_reg[i].z; As[k0 + 3][r] = a_reg[i].w;
        }
#pragma unroll
        for (int i = 0; i < NB; ++i) {
            int idx = i * 1024 + tid * 4;
            int r = idx >> 4, k0 = idx & 15;
            Ws[k0 + 0][r] = w_reg[i].x; Ws[k0 + 1][r] = w_reg[i].y;
            Ws[k0 + 2][r] = w_reg[i].z; Ws[k0 + 3][r] = w_reg[i].w;
        }
        __syncthreads();
#pragma unroll
        for (int k = 0; k < BK; ++k) {
            float a_f[TM], w_f[TN];
#pragma unroll
            for (int i = 0; i < TM; i += 4)
                *(float4*)&a_f[i] = *(const float4*)&As[k][ty * TM + i];
#pragma unroll
            for (int j = 0; j < TN; j += 4)
                *(float4*)&w_f[j] = *(const float4*)&Ws[k][tx * TN + j];
#pragma unroll
            for (int i = 0; i < TM; i++)
#pragma unroll
                for (int j = 0; j < TN; j++)
                    acc[i][j] = fmaf(a_f[i], w_f[j], acc[i][j]);
        }
    }
    // epilogue
#pragma unroll
    for (int i = 0; i < TM; i++) {
        long r = row0 + ty * TM + i;
#pragma unroll
        for (int j = 0; j < TN; j++) {
            long c = col0 + tx * TN + j;
            if (c < N) {
                float v = acc[i][j];
                if (EPI == 5) {
                    v += bias[c];
                    if (c < 256) v = 0.5f * v * (1.f + erff(v * 0.70710678118654752f));
                    else         v = tanhf(v);
                } else if (EPI == 6) { v *= aux[r * 4 + (c >> 4)]; }
                if (EPI == 4) C[r * ldc + c] += v;
                else          C[r * ldc + c] = v;
            }
        }
    }
}

// ---------------------------------------------------------------------------
// causal depthwise conv (DC=4) + SiLU; reads xh-half of xz, writes xh
__global__ __launch_bounds__(256) void conv_silu_k(const float* __restrict__ xz,
                                                   const float* __restrict__ cw,
                                                   const float* __restrict__ cb,
                                                   float* __restrict__ xh)
{
    int c = threadIdx.x;       // 0..255
    int t = blockIdx.x;        // 0..255
    int bn = blockIdx.y;       // 0..127
    float w0 = cw[c * 4 + 0], w1 = cw[c * 4 + 1], w2 = cw[c * 4 + 2], w3 = cw[c * 4 + 3];
    size_t base = ((size_t)bn * TT + t) * 512 + c;
    float acc = cb[c] + w3 * xz[base];
    if (t >= 1) acc += w2 * xz[base - 512];
    if (t >= 2) acc += w1 * xz[base - 1024];
    if (t >= 3) acc += w0 * xz[base - 1536];
    xh[((size_t)bn * TT + t) * DI + c] = acc * sigm(acc);
}

// ---------------------------------------------------------------------------
// dt = softplus(xdbl[:, :8] @ dtw^T + dtb), written into xz[:, 0:256] (stride 512)
__global__ __launch_bounds__(256) void dt_k(const float* __restrict__ xdbl,
                                            const float* __restrict__ dtw,
                                            const float* __restrict__ dtb,
                                            float* __restrict__ dtout)
{
    int n = threadIdx.x;       // 0..255
    int tok = blockIdx.x;
    const float* xr = xdbl + (size_t)tok * 40;
    float acc = dtb[n];
#pragma unroll
    for (int k = 0; k < 8; k++) acc = fmaf(xr[k], dtw[n * 8 + k], acc);
    // stable softplus with fast intrinsics (tolerance is ~1.5e-2; err here ~1e-6)
    float sp = fmaxf(acc, 0.f) + __logf(1.f + __expf(-fabsf(acc)));
    dtout[(size_t)tok * 512 + n] = sp;
}

// ---------------------------------------------------------------------------
// selective scan, 8 states per thread. Thread = (bn, d, s-half).
// Grid: dim3(2, BN_), 256 threads. Block covers 128 d-values x 2 s-halves.
// dt lives in xz[:,0:256]; z in xz[:,256:512]. yg written in-place over xh.
// B/C rows (block-uniform per t) staged in LDS per 64-step chunk.
#define SCH 64
__global__ __launch_bounds__(256) void scan_k(const float* __restrict__ xz,
                                              const float* xh,          // no restrict: aliases yg
                                              const float* __restrict__ xdbl,
                                              const float* __restrict__ A_log,
                                              const float* __restrict__ Dp,
                                              float* yg)
{
    __shared__ float bc[SCH * 32];        // per step: [B0..B15, C0..C15]

    const int tid  = threadIdx.x;
    const int lane = tid & 63;
    const int wave = tid >> 6;            // 0..3
    const int sh   = lane >> 5;           // 0..1 (s-half)
    const int bn   = blockIdx.y;
    const int d    = (blockIdx.x << 7) + (wave << 5) + (lane & 31);
    const size_t tokb = (size_t)bn * TT;

    float A[8];
#pragma unroll
    for (int q = 0; q < 8; ++q)
        A[q] = -__expf(A_log[d * SS + sh * 8 + q]);
    const float Dv = Dp[d];

    float st[8];
#pragma unroll
    for (int q = 0; q < 8; ++q) st[q] = 0.f;

    // preload t=0 per-lane operands
    float dt_c = xz[tokb * 512 + d];
    float xv_c = xh[tokb * DI + d];
    float z_c  = xz[tokb * 512 + 256 + d];

    for (int c0 = 0; c0 < TT; c0 += SCH) {
        __syncthreads();
#pragma unroll
        for (int i = 0; i < SCH * 32 / 256; ++i) {
            int idx = i * 256 + tid;
            int stp = idx >> 5, j = idx & 31;
            bc[idx] = xdbl[(tokb + c0 + stp) * 40 + 8 + j];
        }
        __syncthreads();

        // preload B/C for first step of chunk
        const float* r0 = &bc[sh * 8];
        float4 B0c = *(const float4*)(r0);
        float4 B1c = *(const float4*)(r0 + 4);
        float4 C0c = *(const float4*)(r0 + 16);
        float4 C1c = *(const float4*)(r0 + 20);

        for (int s = 0; s < SCH; ++s) {
            const int t  = c0 + s;
            const int tn = (t < TT - 1) ? t + 1 : t;
            // prefetch next-step per-lane operands (global)
            float dt_n = xz[(tokb + tn) * 512 + d];
            float xv_n = xh[(tokb + tn) * DI + d];
            float z_n  = xz[(tokb + tn) * 512 + 256 + d];
            // prefetch next-step B/C (LDS, clamped at chunk edge)
            const int sn = (s < SCH - 1) ? s + 1 : s;
            const float* rn = &bc[sn * 32 + sh * 8];
            float4 B0n = *(const float4*)(rn);
            float4 B1n = *(const float4*)(rn + 4);
            float4 C0n = *(const float4*)(rn + 16);
            float4 C1n = *(const float4*)(rn + 20);

            float dtx = dt_c * xv_c;
            float dA0 = __expf(A[0] * dt_c);
            float dA1 = __expf(A[1] * dt_c);
            float dA2 = __expf(A[2] * dt_c);
            float dA3 = __expf(A[3] * dt_c);
            float dA4 = __expf(A[4] * dt_c);
            float dA5 = __expf(A[5] * dt_c);
            float dA6 = __expf(A[6] * dt_c);
            float dA7 = __expf(A[7] * dt_c);
            st[0] = fmaf(dA0, st[0], dtx * B0c.x);
            st[1] = fmaf(dA1, st[1], dtx * B0c.y);
            st[2] = fmaf(dA2, st[2], dtx * B0c.z);
            st[3] = fmaf(dA3, st[3], dtx * B0c.w);
            st[4] = fmaf(dA4, st[4], dtx * B1c.x);
            st[5] = fmaf(dA5, st[5], dtx * B1c.y);
            st[6] = fmaf(dA6, st[6], dtx * B1c.z);
            st[7] = fmaf(dA7, st[7], dtx * B1c.w);
            float y0 = st[0] * C0c.x;
            float y1 = st[1] * C0c.y;
            y0 = fmaf(st[2], C0c.z, y0);
            y1 = fmaf(st[3], C0c.w, y1);
            y0 = fmaf(st[4], C1c.x, y0);
            y1 = fmaf(st[5], C1c.y, y1);
            y0 = fmaf(st[6], C1c.z, y0);
            y1 = fmaf(st[7], C1c.w, y1);
            float y = y0 + y1;
            y += __shfl_xor(y, 32, 64);
            float zg = __fdividef(z_c, 1.f + __expf(-z_c));
            float outv = (y + Dv * xv_c) * zg;
            if (sh == 0) yg[(tokb + t) * DI + d] = outv;

            dt_c = dt_n; xv_c = xv_n; z_c = z_n;
            B0c = B0n; B1c = B1n; C0c = C0n; C1c = C1n;
        }
    }
}

// ---------------------------------------------------------------------------
// per-token small projections on fused buffer (stride 512):
// cols 0..127 = gelu(gate1), 128..255 = gelu(mix1)
__global__ __launch_bounds__(64) void gate_k(const float* __restrict__ gmb,
                                             const float* __restrict__ gw2,
                                             const float* __restrict__ gb2,
                                             const float* __restrict__ mw2,
                                             const float* __restrict__ mb2,
                                             const float* __restrict__ Ascale,
                                             float* __restrict__ ws4,
                                             float* __restrict__ dts,
                                             float* __restrict__ gs)
{
    int l = threadIdx.x;       // 0..63
    int tok = blockIdx.x;
    const float* g1 = gmb + (size_t)tok * 512;
    float a0 = g1[l], a1 = g1[l + 64];
    float m0 = g1[128 + l], m1v = g1[192 + l];
    float p[5];
#pragma unroll
    for (int j = 0; j < 5; j++)
        p[j] = a0 * gw2[j * DM + l] + a1 * gw2[j * DM + l + 64];
    float q = m0 * mw2[l] + m1v * mw2[l + 64];
#pragma unroll
    for (int off = 32; off; off >>= 1) {
#pragma unroll
        for (int j = 0; j < 5; j++) p[j] += __shfl_xor(p[j], off, 64);
        q += __shfl_xor(q, off, 64);
    }
    if (l == 0) {
        float go[5];
#pragma unroll
        for (int j = 0; j < 5; j++) go[j] = p[j] + gb2[j];
        float mx = fmaxf(fmaxf(go[0], go[1]), fmaxf(go[2], go[3]));
        float e[4], sum = 0.f;
#pragma unroll
        for (int k = 0; k < 4; k++) { e[k] = expf(go[k] - mx); sum += e[k]; }
        float inv = 1.f / sum;
#pragma unroll
        for (int k = 0; k < 4; k++) ws4[(size_t)tok * 4 + k] = e[k] * inv * Ascale[k];
        dts[tok] = 0.2f * sigm(go[4]);
        gs[tok]  = sigm(q + mb2[0]);
    }
}

// ---------------------------------------------------------------------------
// pack Wu[kr][d] = U[k][d][r], Wv[d][kr] = V[k][r][d]  (both 8192 elems)
__global__ __launch_bounds__(256) void pack_uv_k(const float* __restrict__ U,
                                                 const float* __restrict__ V,
                                                 float* __restrict__ Wu,
                                                 float* __restrict__ Wv)
{
    int i = blockIdx.x * 256 + threadIdx.x;
    if (i < 8192) {
        int kr = i >> 7, d = i & 127;
        int k = kr >> 4, r = kr & 15;
        Wu[i] = U[((size_t)k * DM + d) * RR + r];
        int d2 = i >> 6, kr2 = i & 63;
        int k2 = kr2 >> 4, r2 = kr2 & 15;
        Wv[i] = V[((size_t)k2 * RR + r2) * DM + d2];
    }
}

// ---------------------------------------------------------------------------
// pack Wcat (512x128) = [gw1; mw1; fgw; fbw], bcat(512) = [gb1; mb1; fgb; fbb]
__global__ __launch_bounds__(256) void pack_cat_k(const float* __restrict__ gw1,
                                                  const float* __restrict__ gb1,
                                                  const float* __restrict__ mw1,
                                                  const float* __restrict__ mb1,
                                                  const float* __restrict__ fgw,
                                                  const float* __restrict__ fgb,
                                                  const float* __restrict__ fbw,
                                                  const float* __restrict__ fbb,
                                                  float* __restrict__ Wcat,
                                                  float* __restrict__ bcat)
{
    int i = blockIdx.x * 256 + threadIdx.x;
    if (i < 65536) {
        int r = i >> 7, k = i & 127;
        int sel = r >> 7;         // r/128
        int rr = r & 127;
        const float* src = (sel == 0) ? gw1 : (sel == 1) ? mw1 : (sel == 2) ? fgw : fbw;
        Wcat[i] = src[rr * DM + k];
    }
    if (i < 512) {
        int sel = i >> 7, rr = i & 127;
        const float* src = (sel == 0) ? gb1 : (sel == 1) ? mb1 : (sel == 2) ? fgb : fbb;
        bcat[i] = src[rr];
    }
}

// ---------------------------------------------------------------------------
// final combine + transpose back to (B,T,N,D); gamma/beta live in gmb cols 256..511
__global__ __launch_bounds__(128) void combine_k(const float* __restrict__ h,
                                                 const float* __restrict__ hA,
                                                 const float* __restrict__ hA2,
                                                 const float* __restrict__ gmb,
                                                 const float* __restrict__ dts,
                                                 const float* __restrict__ gs,
                                                 float* __restrict__ out)
{
    int d = threadIdx.x;
    int tok = blockIdx.x;
    int t = tok & 255;
    int bn = tok >> 8;
    int b = bn >> 5, n = bn & 31;
    float dtv = dts[tok], gv = gs[tok];
    size_t i = (size_t)tok * DM + d;
    float u = tanhf(dtv * hA[i] + 0.5f * dtv * dtv * hA2[i]);
    float gamma = gmb[(size_t)tok * 512 + 256 + d];
    float beta  = gmb[(size_t)tok * 512 + 384 + d];
    u = gamma * u + beta;
    out[(((size_t)b * TT + t) * NN + n) * DM + d] = h[i] + gv * u;
}

// ---------------------------------------------------------------------------
extern "C" void kernel_launch(void* const* d_in, const int* in_sizes, int n_in,
                              void* d_out, int out_size, void* d_ws, size_t ws_size,
                              hipStream_t stream)
{
    const float* x       = (const float*)d_in[0];
    const float* in_w    = (const float*)d_in[1];   // (2,512,128)
    const float* conv_w  = (const float*)d_in[2];   // (2,256,4)
    const float* conv_b  = (const float*)d_in[3];   // (2,256)
    const float* xpw     = (const float*)d_in[4];   // (2,40,256)
    const float* dtw     = (const float*)d_in[5];   // (2,256,8)
    const float* dtb     = (const float*)d_in[6];   // (2,256)
    const float* A_log   = (const float*)d_in[7];   // (2,256,16)
    const float* D_skip  = (const float*)d_in[8];   // (2,256)
    const float* ow      = (const float*)d_in[9];   // (2,128,256)
    const float* U       = (const float*)d_in[10];  // (4,128,16)
    const float* V       = (const float*)d_in[11];  // (4,16,128)
    const float* Ascale  = (const float*)d_in[12];  // (4)
    const float* gw1     = (const float*)d_in[13];
    const float* gb1     = (const float*)d_in[14];
    const float* gw2     = (const float*)d_in[15];
    const float* gb2     = (const float*)d_in[16];
    const float* fgw     = (const float*)d_in[17];
    const float* fgb     = (const float*)d_in[18];
    const float* fbw     = (const float*)d_in[19];
    const float* fbb     = (const float*)d_in[20];
    const float* mw1     = (const float*)d_in[21];
    const float* mb1     = (const float*)d_in[22];
    const float* mw2     = (const float*)d_in[23];
    const float* mb2     = (const float*)d_in[24];

    float* ws = (float*)d_ws;
    float* h    = ws;                       //  4,194,304 floats
    float* xz   = h + 4194304;              // 16,777,216 (dt overlays cols 0..255; final: gmb)
    float* xh   = xz + 16777216;            //  8,388,608 (final: hA, hA2)
    float* xdbl = xh + 8388608;             //  1,310,720 (final: Wcat/bcat/Wu/Wv/ws4/dts/gs)
    // total 30,670,848 floats = 122.7 MB

    pack_h_k<<<TOK, 128, 0, stream>>>(x, h);

    for (int l = 0; l < LL; ++l) {
        const float* iw = in_w + (size_t)l * 512 * 128;
        gemm_k<128,128,8,8,0><<<dim3(4,256), 256, 0, stream>>>(
            h, DM, iw, nullptr, xz, 512, TOK, 512, 128, nullptr);
        conv_silu_k<<<dim3(TT, BN_), 256, 0, stream>>>(
            xz, conv_w + (size_t)l * DI * DCV, conv_b + (size_t)l * DI, xh);
        gemm_k<64,64,4,4,0><<<dim3(1,512), 256, 0, stream>>>(
            xh, DI, xpw + (size_t)l * 40 * DI, nullptr, xdbl, 40, TOK, 40, DI, nullptr);
        dt_k<<<TOK, 256, 0, stream>>>(
            xdbl, dtw + (size_t)l * DI * DTR, dtb + (size_t)l * DI, xz);
        scan_k<<<dim3(2, BN_), 256, 0, stream>>>(
            xz, xh, xdbl, A_log + (size_t)l * DI * SS, D_skip + (size_t)l * DI, xh);
        gemm_k<128,128,8,8,4><<<dim3(1,256), 256, 0, stream>>>(
            xh, DI, ow + (size_t)l * DM * DI, nullptr, h, DM, TOK, DM, DI, nullptr);
    }

    // ---------------- final stage ----------------
    // gmb = xz (TOK x 512): cols 0..127 gate1(gelu), 128..255 mix1(gelu),
    //                       256..383 gamma(tanh),   384..511 beta(tanh)
    // Z reuses gmb cols 0..63 (ldc=512) after gate_k consumed gate1/mix1.
    float* gmb  = xz;
    float* Zb   = xz;                       // cols 0..63, stride 512
    float* hA   = xh;                       // TOK*128
    float* hA2  = xh + 4194304;             // TOK*128
    float* Wcat = xdbl;                     // 65,536
    float* bcat = xdbl + 65536;             // 512
    float* Wu   = xdbl + 66048;             // 8,192
    float* Wv   = xdbl + 74240;             // 8,192
    float* ws4  = xdbl + 82432;             // TOK*4 = 131,072
    float* dts  = xdbl + 213504;            // TOK
    float* gs   = xdbl + 246272;            // TOK (ends 279,040 < 1,310,720)

    pack_cat_k<<<256, 256, 0, stream>>>(gw1, gb1, mw1, mb1, fgw, fgb, fbw, fbb, Wcat, bcat);
    gemm_k<128,128,8,8,5><<<dim3(4,256), 256, 0, stream>>>(
        h, DM, Wcat, bcat, gmb, 512, TOK, 512, DM, nullptr);
    gate_k<<<TOK, 64, 0, stream>>>(gmb, gw2, gb2, mw2, mb2, Ascale, ws4, dts, gs);
    pack_uv_k<<<32, 256, 0, stream>>>(U, V, Wu, Wv);

    // amix pass 1: Z = (h @ Wu^T) * w   ;  hA = Z @ Wv^T
    gemm_k<64,64,4,4,6><<<dim3(1,512), 256, 0, stream>>>(
        h, DM, Wu, nullptr, Zb, 512, TOK, 64, DM, ws4);
    gemm_k<64,64,4,4,0><<<dim3(2,512), 256, 0, stream>>>(
        Zb, 512, Wv, nullptr, hA, DM, TOK, DM, 64, nullptr);
    // amix pass 2 on hA
    gemm_k<64,64,4,4,6><<<dim3(1,512), 256, 0, stream>>>(
        hA, DM, Wu, nullptr, Zb, 512, TOK, 64, DM, ws4);
    gemm_k<64,64,4,4,0><<<dim3(2,512), 256, 0, stream>>>(
        Zb, 512, Wv, nullptr, hA2, DM, TOK, DM, 64, nullptr);

    combine_k<<<TOK, 128, 0, stream>>>(h, hA, hA2, gmb, dts, gs, (float*)d_out);
}

// Round 4
// 647.321 us; speedup vs baseline: 1.9672x; 1.4432x over previous
//
#include <hip/hip_runtime.h>
#include <math.h>

// Problem constants
#define BSZ   4
#define TT    256
#define NN    32
#define DM    128
#define LL    2
#define SS    16
#define DCV   4
#define DI    256
#define DTR   8
#define KK    4
#define RR    16
#define BN_   128          // BSZ*NN
#define TOK   32768        // BN_*TT

typedef _Float16 f16x8 __attribute__((ext_vector_type(8)));
typedef float    f32x4 __attribute__((ext_vector_type(4)));

__device__ __forceinline__ float sigm(float x) { return __fdividef(1.f, 1.f + __expf(-x)); }

// ---------------------------------------------------------------------------
// pack x (B,T,N,D) -> h (BN,T,D)
__global__ __launch_bounds__(128) void pack_h_k(const float* __restrict__ x, float* __restrict__ h)
{
    int d = threadIdx.x;
    int tok = blockIdx.x;
    int t = tok & 255;
    int bn = tok >> 8;
    int b = bn >> 5, n = bn & 31;
    h[(size_t)tok * DM + d] = x[(((size_t)b * TT + t) * NN + n) * DM + d];
}

// ---------------------------------------------------------------------------
// MFMA f16 GEMM: C[M,N] = A[M,K] @ W[N,K]^T (+epilogue), fp32 I/O, f16 compute
// Tile 128 (M) x 64 (N), 4 waves, K-chunks of 32, LDS double-buffered.
// EPI: 0 store, 1 +bias(+ACT), 4 C += v, 6 v *= aux[row*4 + (col>>4)+auxb]
// ACT: 0 none, 1 gelu, 2 tanh  (uniform per dispatch)
template<int EPI, int ACT>
__global__ __launch_bounds__(256)
void mgemm_k(const float* __restrict__ A, int lda,
             const float* __restrict__ W,
             const float* __restrict__ bias,
             float* C, int ldc,
             int N, int K,
             const float* __restrict__ aux, int auxb)
{
    // LDS: per buffer: A_s 128 rows x 64B (8KB) + W_s 64 cols x 64B (4KB)
    __shared__ char smem[24576];

    const int tid  = threadIdx.x;
    const int lane = tid & 63;
    const int wv   = tid >> 6;            // 0..3
    const long row0 = (long)blockIdx.y * 128;
    const int  colb = blockIdx.x * 64;    // dispatch-local col base
    const int  NC   = K >> 5;             // 32-k chunks

    // staging assignment: thread -> (row/col = tid>>2, g = tid&3)
    const int st_rc = tid >> 2;           // 0..63
    const int st_g  = tid & 3;
    const int offA0 = st_rc * 64        + ((st_g ^ (st_rc & 3)) << 4);
    const int offA1 = (st_rc + 64) * 64 + ((st_g ^ (st_rc & 3)) << 4);
    const int offW  = st_rc * 64        + ((st_g ^ (st_rc & 3)) << 4);
    const int wcol  = colb + st_rc;
    const bool wok  = (wcol < N);

    // fragment read offsets (chunk-invariant)
    const int fr = lane & 15;
    const int fg = lane >> 4;
    const int ra0 = (wv << 5) + fr;
    const int offa0 = ra0 * 64        + ((fg ^ (ra0 & 3)) << 4);
    const int offa1 = (ra0 + 16) * 64 + ((fg ^ (ra0 & 3)) << 4);
    int offb[4];
#pragma unroll
    for (int nj = 0; nj < 4; ++nj) {
        int cb = (nj << 4) + fr;
        offb[nj] = cb * 64 + ((fg ^ (fr & 3)) << 4);
    }

    f32x4 acc[2][4];
#pragma unroll
    for (int mi = 0; mi < 2; ++mi)
#pragma unroll
        for (int nj = 0; nj < 4; ++nj) acc[mi][nj] = (f32x4){0.f, 0.f, 0.f, 0.f};

    float va0[8], va1[8], vw[8];

    // ---- gload(0)
    {
        const float* pa0 = A + (row0 + st_rc) * (long)lda + st_g * 8;
        *(float4*)&va0[0] = *(const float4*)pa0;
        *(float4*)&va0[4] = *(const float4*)(pa0 + 4);
        const float* pa1 = pa0 + 64 * (long)lda;
        *(float4*)&va1[0] = *(const float4*)pa1;
        *(float4*)&va1[4] = *(const float4*)(pa1 + 4);
        if (wok) {
            const float* pw = W + (long)wcol * K + st_g * 8;
            *(float4*)&vw[0] = *(const float4*)pw;
            *(float4*)&vw[4] = *(const float4*)(pw + 4);
        } else {
#pragma unroll
            for (int j = 0; j < 8; ++j) vw[j] = 0.f;
        }
    }
    // ---- swrite(0)
    {
        char* base = smem;
        f16x8 h0, h1, hw;
#pragma unroll
        for (int j = 0; j < 8; ++j) { h0[j] = (_Float16)va0[j]; h1[j] = (_Float16)va1[j]; hw[j] = (_Float16)vw[j]; }
        *(f16x8*)(base + offA0) = h0;
        *(f16x8*)(base + offA1) = h1;
        *(f16x8*)(base + 8192 + offW) = hw;
    }
    __syncthreads();

    for (int c = 0; c < NC; ++c) {
        if (c + 1 < NC) {
            const int kk = (c + 1) << 5;
            const float* pa0 = A + (row0 + st_rc) * (long)lda + kk + st_g * 8;
            *(float4*)&va0[0] = *(const float4*)pa0;
            *(float4*)&va0[4] = *(const float4*)(pa0 + 4);
            const float* pa1 = pa0 + 64 * (long)lda;
            *(float4*)&va1[0] = *(const float4*)pa1;
            *(float4*)&va1[4] = *(const float4*)(pa1 + 4);
            if (wok) {
                const float* pw = W + (long)wcol * K + kk + st_g * 8;
                *(float4*)&vw[0] = *(const float4*)pw;
                *(float4*)&vw[4] = *(const float4*)(pw + 4);
            }
        }
        // compute chunk c from buffer c&1
        {
            const char* As = smem + (c & 1) * 12288;
            const char* Ws = As + 8192;
            f16x8 af0 = *(const f16x8*)(As + offa0);
            f16x8 af1 = *(const f16x8*)(As + offa1);
            f16x8 bf[4];
#pragma unroll
            for (int nj = 0; nj < 4; ++nj) bf[nj] = *(const f16x8*)(Ws + offb[nj]);
#pragma unroll
            for (int nj = 0; nj < 4; ++nj) {
                acc[0][nj] = __builtin_amdgcn_mfma_f32_16x16x32_f16(af0, bf[nj], acc[0][nj], 0, 0, 0);
                acc[1][nj] = __builtin_amdgcn_mfma_f32_16x16x32_f16(af1, bf[nj], acc[1][nj], 0, 0, 0);
            }
        }
        if (c + 1 < NC) {
            char* base = smem + ((c + 1) & 1) * 12288;
            f16x8 h0, h1, hw;
#pragma unroll
            for (int j = 0; j < 8; ++j) { h0[j] = (_Float16)va0[j]; h1[j] = (_Float16)va1[j]; hw[j] = (_Float16)vw[j]; }
            *(f16x8*)(base + offA0) = h0;
            *(f16x8*)(base + offA1) = h1;
            *(f16x8*)(base + 8192 + offW) = hw;
        }
        __syncthreads();
    }

    // ---- epilogue
#pragma unroll
    for (int nj = 0; nj < 4; ++nj) {
        int col = colb + (nj << 4) + fr;      // dispatch-local col
        if (col < N) {
            float bb = 0.f;
            if (EPI == 1 && bias) bb = bias[col];
#pragma unroll
            for (int mi = 0; mi < 2; ++mi) {
                long rg = row0 + (wv << 5) + (mi << 4) + (fg << 2);
#pragma unroll
                for (int r = 0; r < 4; ++r) {
                    float v = acc[mi][nj][r];
                    if (EPI == 1) {
                        v += bb;
                        if (ACT == 1) v = 0.5f * v * (1.f + erff(v * 0.70710678118654752f));
                        else if (ACT == 2) v = tanhf(v);
                    } else if (EPI == 6) {
                        v *= aux[(rg + r) * 4 + ((col >> 4) + auxb)];
                    }
                    float* pc = C + (rg + r) * (long)ldc + col;
                    if (EPI == 4) *pc += v;
                    else          *pc = v;
                }
            }
        }
    }
}

// ---------------------------------------------------------------------------
// fp32 tiled GEMM (kept for the precision-sensitive x_dbl projection)
template<int BM, int BN, int TM, int TN, int EPI>
__global__ __launch_bounds__(256)
void gemm_k(const float* __restrict__ A, int lda,
            const float* __restrict__ W,
            const float* __restrict__ bias,
            float* C, int ldc,
            int M, int N, int K,
            const float* __restrict__ aux)
{
    constexpr int BK = 16;
    constexpr int LDS_A = BM + 4;
    constexpr int LDS_B = BN + 4;
    static_assert((BM / TM) * (BN / TN) == 256, "256 threads");
    constexpr int NA = BM * BK / 1024;
    constexpr int NB = BN * BK / 1024;

    __shared__ float As[BK][LDS_A];
    __shared__ float Ws[BK][LDS_B];

    const int tid = threadIdx.x;
    constexpr int nx = BN / TN;
    const int tx = tid % nx, ty = tid / nx;
    const long row0 = (long)blockIdx.y * BM;
    const long col0 = (long)blockIdx.x * BN;

    float acc[TM][TN];
#pragma unroll
    for (int i = 0; i < TM; i++)
#pragma unroll
        for (int j = 0; j < TN; j++) acc[i][j] = 0.f;

    for (int kk = 0; kk < K; kk += BK) {
        float4 a_reg[NA], w_reg[NB];
#pragma unroll
        for (int i = 0; i < NA; ++i) {
            int idx = i * 1024 + tid * 4;
            int r = idx >> 4, k0 = idx & 15;
            int k = kk + k0;
            const float* p = A + (row0 + r) * (long)lda + k;
            a_reg[i] = *(const float4*)p;
        }
#pragma unroll
        for (int i = 0; i < NB; ++i) {
            int idx = i * 1024 + tid * 4;
            int r = idx >> 4, k0 = idx & 15;
            long gc = col0 + r;
            int k = kk + k0;
            if (gc < N) {
                const float* p = W + gc * (long)K + k;
                w_reg[i] = *(const float4*)p;
            } else w_reg[i] = make_float4(0.f, 0.f, 0.f, 0.f);
        }
        __syncthreads();
#pragma unroll
        for (int i = 0; i < NA; ++i) {
            int idx = i * 1024 + tid * 4;
            int r = idx >> 4, k0 = idx & 15;
            As[k0 + 0][r] = a_reg[i].x; As[k0 + 1][r] = a_reg[i].y;
            As[k0 + 2][r] = a_reg[i].z; As[k0 + 3][r] = a_reg[i].w;
        }
#pragma unroll
        for (int i = 0; i < NB; ++i) {
            int idx = i * 1024 + tid * 4;
            int r = idx >> 4, k0 = idx & 15;
            Ws[k0 + 0][r] = w_reg[i].x; Ws[k0 + 1][r] = w_reg[i].y;
            Ws[k0 + 2][r] = w_reg[i].z; Ws[k0 + 3][r] = w_reg[i].w;
        }
        __syncthreads();
#pragma unroll
        for (int k = 0; k < BK; ++k) {
            float a_f[TM], w_f[TN];
#pragma unroll
            for (int i = 0; i < TM; i += 4)
                *(float4*)&a_f[i] = *(const float4*)&As[k][ty * TM + i];
#pragma unroll
            for (int j = 0; j < TN; j += 4)
                *(float4*)&w_f[j] = *(const float4*)&Ws[k][tx * TN + j];
#pragma unroll
            for (int i = 0; i < TM; i++)
#pragma unroll
                for (int j = 0; j < TN; j++)
                    acc[i][j] = fmaf(a_f[i], w_f[j], acc[i][j]);
        }
    }
#pragma unroll
    for (int i = 0; i < TM; i++) {
        long r = row0 + ty * TM + i;
#pragma unroll
        for (int j = 0; j < TN; j++) {
            long c = col0 + tx * TN + j;
            if (c < N) C[r * ldc + c] = acc[i][j];
        }
    }
}

// ---------------------------------------------------------------------------
// causal depthwise conv (DC=4) + SiLU; reads xh-half of xz, writes xh
__global__ __launch_bounds__(256) void conv_silu_k(const float* __restrict__ xz,
                                                   const float* __restrict__ cw,
                                                   const float* __restrict__ cb,
                                                   float* __restrict__ xh)
{
    int c = threadIdx.x;       // 0..255
    int t = blockIdx.x;        // 0..255
    int bn = blockIdx.y;       // 0..127
    float w0 = cw[c * 4 + 0], w1 = cw[c * 4 + 1], w2 = cw[c * 4 + 2], w3 = cw[c * 4 + 3];
    size_t base = ((size_t)bn * TT + t) * 512 + c;
    float acc = cb[c] + w3 * xz[base];
    if (t >= 1) acc += w2 * xz[base - 512];
    if (t >= 2) acc += w1 * xz[base - 1024];
    if (t >= 3) acc += w0 * xz[base - 1536];
    xh[((size_t)bn * TT + t) * DI + c] = acc * sigm(acc);
}

// ---------------------------------------------------------------------------
// dt = softplus(xdbl[:, :8] @ dtw^T + dtb), written into xz[:, 0:256] (stride 512)
__global__ __launch_bounds__(256) void dt_k(const float* __restrict__ xdbl,
                                            const float* __restrict__ dtw,
                                            const float* __restrict__ dtb,
                                            float* __restrict__ dtout)
{
    int n = threadIdx.x;       // 0..255
    int tok = blockIdx.x;
    const float* xr = xdbl + (size_t)tok * 40;
    float acc = dtb[n];
#pragma unroll
    for (int k = 0; k < 8; k++) acc = fmaf(xr[k], dtw[n * 8 + k], acc);
    float sp = fmaxf(acc, 0.f) + __logf(1.f + __expf(-fabsf(acc)));
    dtout[(size_t)tok * 512 + n] = sp;
}

// ---------------------------------------------------------------------------
// selective scan, 8 states per thread. Thread = (bn, d, s-half).
#define SCH 64
__global__ __launch_bounds__(256) void scan_k(const float* __restrict__ xz,
                                              const float* xh,          // no restrict: aliases yg
                                              const float* __restrict__ xdbl,
                                              const float* __restrict__ A_log,
                                              const float* __restrict__ Dp,
                                              float* yg)
{
    __shared__ float bc[SCH * 32];        // per step: [B0..B15, C0..C15]

    const int tid  = threadIdx.x;
    const int lane = tid & 63;
    const int wave = tid >> 6;
    const int sh   = lane >> 5;           // 0..1 (s-half)
    const int bn   = blockIdx.y;
    const int d    = (blockIdx.x << 7) + (wave << 5) + (lane & 31);
    const size_t tokb = (size_t)bn * TT;

    float A[8];
#pragma unroll
    for (int q = 0; q < 8; ++q)
        A[q] = -__expf(A_log[d * SS + sh * 8 + q]);
    const float Dv = Dp[d];

    float st[8];
#pragma unroll
    for (int q = 0; q < 8; ++q) st[q] = 0.f;

    float dt_c = xz[tokb * 512 + d];
    float xv_c = xh[tokb * DI + d];
    float z_c  = xz[tokb * 512 + 256 + d];

    for (int c0 = 0; c0 < TT; c0 += SCH) {
        __syncthreads();
#pragma unroll
        for (int i = 0; i < SCH * 32 / 256; ++i) {
            int idx = i * 256 + tid;
            int stp = idx >> 5, j = idx & 31;
            bc[idx] = xdbl[(tokb + c0 + stp) * 40 + 8 + j];
        }
        __syncthreads();

        const float* r0 = &bc[sh * 8];
        float4 B0c = *(const float4*)(r0);
        float4 B1c = *(const float4*)(r0 + 4);
        float4 C0c = *(const float4*)(r0 + 16);
        float4 C1c = *(const float4*)(r0 + 20);

        for (int s = 0; s < SCH; ++s) {
            const int t  = c0 + s;
            const int tn = (t < TT - 1) ? t + 1 : t;
            float dt_n = xz[(tokb + tn) * 512 + d];
            float xv_n = xh[(tokb + tn) * DI + d];
            float z_n  = xz[(tokb + tn) * 512 + 256 + d];
            const int sn = (s < SCH - 1) ? s + 1 : s;
            const float* rn = &bc[sn * 32 + sh * 8];
            float4 B0n = *(const float4*)(rn);
            float4 B1n = *(const float4*)(rn + 4);
            float4 C0n = *(const float4*)(rn + 16);
            float4 C1n = *(const float4*)(rn + 20);

            float dtx = dt_c * xv_c;
            float dA0 = __expf(A[0] * dt_c);
            float dA1 = __expf(A[1] * dt_c);
            float dA2 = __expf(A[2] * dt_c);
            float dA3 = __expf(A[3] * dt_c);
            float dA4 = __expf(A[4] * dt_c);
            float dA5 = __expf(A[5] * dt_c);
            float dA6 = __expf(A[6] * dt_c);
            float dA7 = __expf(A[7] * dt_c);
            st[0] = fmaf(dA0, st[0], dtx * B0c.x);
            st[1] = fmaf(dA1, st[1], dtx * B0c.y);
            st[2] = fmaf(dA2, st[2], dtx * B0c.z);
            st[3] = fmaf(dA3, st[3], dtx * B0c.w);
            st[4] = fmaf(dA4, st[4], dtx * B1c.x);
            st[5] = fmaf(dA5, st[5], dtx * B1c.y);
            st[6] = fmaf(dA6, st[6], dtx * B1c.z);
            st[7] = fmaf(dA7, st[7], dtx * B1c.w);
            float y0 = st[0] * C0c.x;
            float y1 = st[1] * C0c.y;
            y0 = fmaf(st[2], C0c.z, y0);
            y1 = fmaf(st[3], C0c.w, y1);
            y0 = fmaf(st[4], C1c.x, y0);
            y1 = fmaf(st[5], C1c.y, y1);
            y0 = fmaf(st[6], C1c.z, y0);
            y1 = fmaf(st[7], C1c.w, y1);
            float y = y0 + y1;
            y += __shfl_xor(y, 32, 64);
            float zg = __fdividef(z_c, 1.f + __expf(-z_c));
            float outv = (y + Dv * xv_c) * zg;
            if (sh == 0) yg[(tokb + t) * DI + d] = outv;

            dt_c = dt_n; xv_c = xv_n; z_c = z_n;
            B0c = B0n; B1c = B1n; C0c = C0n; C1c = C1n;
        }
    }
}

// ---------------------------------------------------------------------------
// per-token small projections on fused buffer (stride 512)
__global__ __launch_bounds__(64) void gate_k(const float* __restrict__ gmb,
                                             const float* __restrict__ gw2,
                                             const float* __restrict__ gb2,
                                             const float* __restrict__ mw2,
                                             const float* __restrict__ mb2,
                                             const float* __restrict__ Ascale,
                                             float* __restrict__ ws4,
                                             float* __restrict__ dts,
                                             float* __restrict__ gs)
{
    int l = threadIdx.x;       // 0..63
    int tok = blockIdx.x;
    const float* g1 = gmb + (size_t)tok * 512;
    float a0 = g1[l], a1 = g1[l + 64];
    float m0 = g1[128 + l], m1v = g1[192 + l];
    float p[5];
#pragma unroll
    for (int j = 0; j < 5; j++)
        p[j] = a0 * gw2[j * DM + l] + a1 * gw2[j * DM + l + 64];
    float q = m0 * mw2[l] + m1v * mw2[l + 64];
#pragma unroll
    for (int off = 32; off; off >>= 1) {
#pragma unroll
        for (int j = 0; j < 5; j++) p[j] += __shfl_xor(p[j], off, 64);
        q += __shfl_xor(q, off, 64);
    }
    if (l == 0) {
        float go[5];
#pragma unroll
        for (int j = 0; j < 5; j++) go[j] = p[j] + gb2[j];
        float mx = fmaxf(fmaxf(go[0], go[1]), fmaxf(go[2], go[3]));
        float e[4], sum = 0.f;
#pragma unroll
        for (int k = 0; k < 4; k++) { e[k] = expf(go[k] - mx); sum += e[k]; }
        float inv = 1.f / sum;
#pragma unroll
        for (int k = 0; k < 4; k++) ws4[(size_t)tok * 4 + k] = e[k] * inv * Ascale[k];
        dts[tok] = 0.2f * sigm(go[4]);
        gs[tok]  = sigm(q + mb2[0]);
    }
}

// ---------------------------------------------------------------------------
// pack Wu[kr][d] = U[k][d][r], Wv[d][kr] = V[k][r][d]  (both 8192 elems)
__global__ __launch_bounds__(256) void pack_uv_k(const float* __restrict__ U,
                                                 const float* __restrict__ V,
                                                 float* __restrict__ Wu,
                                                 float* __restrict__ Wv)
{
    int i = blockIdx.x * 256 + threadIdx.x;
    if (i < 8192) {
        int kr = i >> 7, d = i & 127;
        int k = kr >> 4, r = kr & 15;
        Wu[i] = U[((size_t)k * DM + d) * RR + r];
        int d2 = i >> 6, kr2 = i & 63;
        int k2 = kr2 >> 4, r2 = kr2 & 15;
        Wv[i] = V[((size_t)k2 * RR + r2) * DM + d2];
    }
}

// ---------------------------------------------------------------------------
// pack Wcat (512x128) = [gw1; mw1; fgw; fbw], bcat(512)
__global__ __launch_bounds__(256) void pack_cat_k(const float* __restrict__ gw1,
                                                  const float* __restrict__ gb1,
                                                  const float* __restrict__ mw1,
                                                  const float* __restrict__ mb1,
                                                  const float* __restrict__ fgw,
                                                  const float* __restrict__ fgb,
                                                  const float* __restrict__ fbw,
                                                  const float* __restrict__ fbb,
                                                  float* __restrict__ Wcat,
                                                  float* __restrict__ bcat)
{
    int i = blockIdx.x * 256 + threadIdx.x;
    if (i < 65536) {
        int r = i >> 7, k = i & 127;
        int sel = r >> 7;
        int rr = r & 127;
        const float* src = (sel == 0) ? gw1 : (sel == 1) ? mw1 : (sel == 2) ? fgw : fbw;
        Wcat[i] = src[rr * DM + k];
    }
    if (i < 512) {
        int sel = i >> 7, rr = i & 127;
        const float* src = (sel == 0) ? gb1 : (sel == 1) ? mb1 : (sel == 2) ? fgb : fbb;
        bcat[i] = src[rr];
    }
}

// ---------------------------------------------------------------------------
// final combine + transpose back to (B,T,N,D)
__global__ __launch_bounds__(128) void combine_k(const float* __restrict__ h,
                                                 const float* __restrict__ hA,
                                                 const float* __restrict__ hA2,
                                                 const float* __restrict__ gmb,
                                                 const float* __restrict__ dts,
                                                 const float* __restrict__ gs,
                                                 float* __restrict__ out)
{
    int d = threadIdx.x;
    int tok = blockIdx.x;
    int t = tok & 255;
    int bn = tok >> 8;
    int b = bn >> 5, n = bn & 31;
    float dtv = dts[tok], gv = gs[tok];
    size_t i = (size_t)tok * DM + d;
    float u = tanhf(dtv * hA[i] + 0.5f * dtv * dtv * hA2[i]);
    float gamma = gmb[(size_t)tok * 512 + 256 + d];
    float beta  = gmb[(size_t)tok * 512 + 384 + d];
    u = gamma * u + beta;
    out[(((size_t)b * TT + t) * NN + n) * DM + d] = h[i] + gv * u;
}

// ---------------------------------------------------------------------------
extern "C" void kernel_launch(void* const* d_in, const int* in_sizes, int n_in,
                              void* d_out, int out_size, void* d_ws, size_t ws_size,
                              hipStream_t stream)
{
    const float* x       = (const float*)d_in[0];
    const float* in_w    = (const float*)d_in[1];   // (2,512,128)
    const float* conv_w  = (const float*)d_in[2];   // (2,256,4)
    const float* conv_b  = (const float*)d_in[3];   // (2,256)
    const float* xpw     = (const float*)d_in[4];   // (2,40,256)
    const float* dtw     = (const float*)d_in[5];   // (2,256,8)
    const float* dtb     = (const float*)d_in[6];   // (2,256)
    const float* A_log   = (const float*)d_in[7];   // (2,256,16)
    const float* D_skip  = (const float*)d_in[8];   // (2,256)
    const float* ow      = (const float*)d_in[9];   // (2,128,256)
    const float* U       = (const float*)d_in[10];  // (4,128,16)
    const float* V       = (const float*)d_in[11];  // (4,16,128)
    const float* Ascale  = (const float*)d_in[12];  // (4)
    const float* gw1     = (const float*)d_in[13];
    const float* gb1     = (const float*)d_in[14];
    const float* gw2     = (const float*)d_in[15];
    const float* gb2     = (const float*)d_in[16];
    const float* fgw     = (const float*)d_in[17];
    const float* fgb     = (const float*)d_in[18];
    const float* fbw     = (const float*)d_in[19];
    const float* fbb     = (const float*)d_in[20];
    const float* mw1     = (const float*)d_in[21];
    const float* mb1     = (const float*)d_in[22];
    const float* mw2     = (const float*)d_in[23];
    const float* mb2     = (const float*)d_in[24];

    float* ws = (float*)d_ws;
    float* h    = ws;                       //  4,194,304 floats
    float* xz   = h + 4194304;              // 16,777,216 (dt cols 0..255; final: gmb)
    float* xh   = xz + 16777216;            //  8,388,608 (final: hA, hA2)
    float* xdbl = xh + 8388608;             //  1,310,720 (final: Wcat/bcat/Wu/Wv/ws4/dts/gs)
    // total 30,670,848 floats = 122.7 MB

    pack_h_k<<<TOK, 128, 0, stream>>>(x, h);

    for (int l = 0; l < LL; ++l) {
        const float* iw = in_w + (size_t)l * 512 * 128;
        // in_proj: f16 MFMA, N=512, K=128
        mgemm_k<0,0><<<dim3(8,256), 256, 0, stream>>>(
            h, DM, iw, nullptr, xz, 512, 512, 128, nullptr, 0);
        conv_silu_k<<<dim3(TT, BN_), 256, 0, stream>>>(
            xz, conv_w + (size_t)l * DI * DCV, conv_b + (size_t)l * DI, xh);
        // x_dbl: keep fp32 (feeds dt/B/C into the exp-sensitive scan)
        gemm_k<64,64,4,4,0><<<dim3(1,512), 256, 0, stream>>>(
            xh, DI, xpw + (size_t)l * 40 * DI, nullptr, xdbl, 40, TOK, 40, DI, nullptr);
        dt_k<<<TOK, 256, 0, stream>>>(
            xdbl, dtw + (size_t)l * DI * DTR, dtb + (size_t)l * DI, xz);
        scan_k<<<dim3(2, BN_), 256, 0, stream>>>(
            xz, xh, xdbl, A_log + (size_t)l * DI * SS, D_skip + (size_t)l * DI, xh);
        // out_proj: f16 MFMA, accumulate into h, N=128, K=256
        mgemm_k<4,0><<<dim3(2,256), 256, 0, stream>>>(
            xh, DI, ow + (size_t)l * DM * DI, nullptr, h, DM, 128, 256, nullptr, 0);
    }

    // ---------------- final stage ----------------
    float* gmb  = xz;
    float* Zb   = xz;                       // cols 0..63, stride 512
    float* hA   = xh;
    float* hA2  = xh + 4194304;
    float* Wcat = xdbl;                     // 65,536
    float* bcat = xdbl + 65536;             // 512
    float* Wu   = xdbl + 66048;             // 8,192
    float* Wv   = xdbl + 74240;             // 8,192
    float* ws4  = xdbl + 82432;             // TOK*4
    float* dts  = xdbl + 213504;            // TOK
    float* gs   = xdbl + 246272;            // TOK

    pack_cat_k<<<256, 256, 0, stream>>>(gw1, gb1, mw1, mb1, fgw, fgb, fbw, fbb, Wcat, bcat);
    // fused gate/mix (gelu) cols 0..255 and film gamma/beta (tanh) cols 256..511
    mgemm_k<1,1><<<dim3(4,256), 256, 0, stream>>>(
        h, DM, Wcat, bcat, gmb, 512, 256, 128, nullptr, 0);
    mgemm_k<1,2><<<dim3(4,256), 256, 0, stream>>>(
        h, DM, Wcat + 256 * 128, bcat + 256, gmb + 256, 512, 256, 128, nullptr, 0);
    gate_k<<<TOK, 64, 0, stream>>>(gmb, gw2, gb2, mw2, mb2, Ascale, ws4, dts, gs);
    pack_uv_k<<<32, 256, 0, stream>>>(U, V, Wu, Wv);

    // amix pass 1: Z = (h @ Wu^T) * w   ;  hA = Z @ Wv^T
    mgemm_k<6,0><<<dim3(1,256), 256, 0, stream>>>(
        h, DM, Wu, nullptr, Zb, 512, 64, 128, ws4, 0);
    mgemm_k<0,0><<<dim3(2,256), 256, 0, stream>>>(
        Zb, 512, Wv, nullptr, hA, DM, 128, 64, nullptr, 0);
    // amix pass 2 on hA
    mgemm_k<6,0><<<dim3(1,256), 256, 0, stream>>>(
        hA, DM, Wu, nullptr, Zb, 512, 64, 128, ws4, 0);
    mgemm_k<0,0><<<dim3(2,256), 256, 0, stream>>>(
        Zb, 512, Wv, nullptr, hA2, DM, 128, 64, nullptr, 0);

    combine_k<<<TOK, 128, 0, stream>>>(h, hA, hA2, gmb, dts, gs, (float*)d_out);
}

// Round 5
// 584.201 us; speedup vs baseline: 2.1798x; 1.1080x over previous
//
#include <hip/hip_runtime.h>
#include <math.h>

// Problem constants
#define BSZ   4
#define TT    256
#define NN    32
#define DM    128
#define LL    2
#define SS    16
#define DCV   4
#define DI    256
#define DTR   8
#define KK    4
#define RR    16
#define BN_   128          // BSZ*NN
#define TOK   32768        // BN_*TT

typedef _Float16 f16x8 __attribute__((ext_vector_type(8)));
typedef float    f32x4 __attribute__((ext_vector_type(4)));

__device__ __forceinline__ float sigm(float x) { return __fdividef(1.f, 1.f + __expf(-x)); }

// ---------------------------------------------------------------------------
// pack x (B,T,N,D) -> h (BN,T,D)
__global__ __launch_bounds__(256) void pack_h_k(const float* __restrict__ x, float* __restrict__ h)
{
    int tid = threadIdx.x;
    int d = tid & 127;
    int tok = blockIdx.x * 2 + (tid >> 7);
    int t = tok & 255;
    int bn = tok >> 8;
    int b = bn >> 5, n = bn & 31;
    h[(size_t)tok * DM + d] = x[(((size_t)b * TT + t) * NN + n) * DM + d];
}

// ---------------------------------------------------------------------------
// MFMA f16 GEMM: C[M,N] = A[M,K] @ W[N,K]^T (+epilogue), fp32 I/O, f16 compute
// Tile 128 (M) x 64 (N), 4 waves, K-chunks of 32, LDS double-buffered.
// EPI: 0 store, 1 +bias(+ACT), 4 C += v, 6 v *= aux[row*4 + (col>>4)+auxb]
// ACT: 0 none, 1 gelu, 2 tanh  (uniform per dispatch)
template<int EPI, int ACT>
__global__ __launch_bounds__(256)
void mgemm_k(const float* __restrict__ A, int lda,
             const float* __restrict__ W,
             const float* __restrict__ bias,
             float* C, int ldc,
             int N, int K,
             const float* __restrict__ aux, int auxb)
{
    __shared__ char smem[24576];

    const int tid  = threadIdx.x;
    const int lane = tid & 63;
    const int wv   = tid >> 6;            // 0..3
    const long row0 = (long)blockIdx.y * 128;
    const int  colb = blockIdx.x * 64;    // dispatch-local col base
    const int  NC   = K >> 5;             // 32-k chunks

    const int st_rc = tid >> 2;           // 0..63
    const int st_g  = tid & 3;
    const int offA0 = st_rc * 64        + ((st_g ^ (st_rc & 3)) << 4);
    const int offA1 = (st_rc + 64) * 64 + ((st_g ^ (st_rc & 3)) << 4);
    const int offW  = st_rc * 64        + ((st_g ^ (st_rc & 3)) << 4);
    const int wcol  = colb + st_rc;
    const bool wok  = (wcol < N);

    const int fr = lane & 15;
    const int fg = lane >> 4;
    const int ra0 = (wv << 5) + fr;
    const int offa0 = ra0 * 64        + ((fg ^ (ra0 & 3)) << 4);
    const int offa1 = (ra0 + 16) * 64 + ((fg ^ (ra0 & 3)) << 4);
    int offb[4];
#pragma unroll
    for (int nj = 0; nj < 4; ++nj) {
        int cb = (nj << 4) + fr;
        offb[nj] = cb * 64 + ((fg ^ (fr & 3)) << 4);
    }

    f32x4 acc[2][4];
#pragma unroll
    for (int mi = 0; mi < 2; ++mi)
#pragma unroll
        for (int nj = 0; nj < 4; ++nj) acc[mi][nj] = (f32x4){0.f, 0.f, 0.f, 0.f};

    float va0[8], va1[8], vw[8];

    {
        const float* pa0 = A + (row0 + st_rc) * (long)lda + st_g * 8;
        *(float4*)&va0[0] = *(const float4*)pa0;
        *(float4*)&va0[4] = *(const float4*)(pa0 + 4);
        const float* pa1 = pa0 + 64 * (long)lda;
        *(float4*)&va1[0] = *(const float4*)pa1;
        *(float4*)&va1[4] = *(const float4*)(pa1 + 4);
        if (wok) {
            const float* pw = W + (long)wcol * K + st_g * 8;
            *(float4*)&vw[0] = *(const float4*)pw;
            *(float4*)&vw[4] = *(const float4*)(pw + 4);
        } else {
#pragma unroll
            for (int j = 0; j < 8; ++j) vw[j] = 0.f;
        }
    }
    {
        char* base = smem;
        f16x8 h0, h1, hw;
#pragma unroll
        for (int j = 0; j < 8; ++j) { h0[j] = (_Float16)va0[j]; h1[j] = (_Float16)va1[j]; hw[j] = (_Float16)vw[j]; }
        *(f16x8*)(base + offA0) = h0;
        *(f16x8*)(base + offA1) = h1;
        *(f16x8*)(base + 8192 + offW) = hw;
    }
    __syncthreads();

    for (int c = 0; c < NC; ++c) {
        if (c + 1 < NC) {
            const int kk = (c + 1) << 5;
            const float* pa0 = A + (row0 + st_rc) * (long)lda + kk + st_g * 8;
            *(float4*)&va0[0] = *(const float4*)pa0;
            *(float4*)&va0[4] = *(const float4*)(pa0 + 4);
            const float* pa1 = pa0 + 64 * (long)lda;
            *(float4*)&va1[0] = *(const float4*)pa1;
            *(float4*)&va1[4] = *(const float4*)(pa1 + 4);
            if (wok) {
                const float* pw = W + (long)wcol * K + kk + st_g * 8;
                *(float4*)&vw[0] = *(const float4*)pw;
                *(float4*)&vw[4] = *(const float4*)(pw + 4);
            }
        }
        {
            const char* As = smem + (c & 1) * 12288;
            const char* Ws = As + 8192;
            f16x8 af0 = *(const f16x8*)(As + offa0);
            f16x8 af1 = *(const f16x8*)(As + offa1);
            f16x8 bf[4];
#pragma unroll
            for (int nj = 0; nj < 4; ++nj) bf[nj] = *(const f16x8*)(Ws + offb[nj]);
#pragma unroll
            for (int nj = 0; nj < 4; ++nj) {
                acc[0][nj] = __builtin_amdgcn_mfma_f32_16x16x32_f16(af0, bf[nj], acc[0][nj], 0, 0, 0);
                acc[1][nj] = __builtin_amdgcn_mfma_f32_16x16x32_f16(af1, bf[nj], acc[1][nj], 0, 0, 0);
            }
        }
        if (c + 1 < NC) {
            char* base = smem + ((c + 1) & 1) * 12288;
            f16x8 h0, h1, hw;
#pragma unroll
            for (int j = 0; j < 8; ++j) { h0[j] = (_Float16)va0[j]; h1[j] = (_Float16)va1[j]; hw[j] = (_Float16)vw[j]; }
            *(f16x8*)(base + offA0) = h0;
            *(f16x8*)(base + offA1) = h1;
            *(f16x8*)(base + 8192 + offW) = hw;
        }
        __syncthreads();
    }

#pragma unroll
    for (int nj = 0; nj < 4; ++nj) {
        int col = colb + (nj << 4) + fr;
        if (col < N) {
            float bb = 0.f;
            if (EPI == 1 && bias) bb = bias[col];
#pragma unroll
            for (int mi = 0; mi < 2; ++mi) {
                long rg = row0 + (wv << 5) + (mi << 4) + (fg << 2);
#pragma unroll
                for (int r = 0; r < 4; ++r) {
                    float v = acc[mi][nj][r];
                    if (EPI == 1) {
                        v += bb;
                        if (ACT == 1) v = 0.5f * v * (1.f + erff(v * 0.70710678118654752f));
                        else if (ACT == 2) v = tanhf(v);
                    } else if (EPI == 6) {
                        v *= aux[(rg + r) * 4 + ((col >> 4) + auxb)];
                    }
                    float* pc = C + (rg + r) * (long)ldc + col;
                    if (EPI == 4) *pc += v;
                    else          *pc = v;
                }
            }
        }
    }
}

// ---------------------------------------------------------------------------
// fp32 tiled GEMM (kept for the precision-sensitive x_dbl projection)
template<int BM, int BN, int TM, int TN, int EPI>
__global__ __launch_bounds__(256)
void gemm_k(const float* __restrict__ A, int lda,
            const float* __restrict__ W,
            const float* __restrict__ bias,
            float* C, int ldc,
            int M, int N, int K,
            const float* __restrict__ aux)
{
    constexpr int BK = 16;
    constexpr int LDS_A = BM + 4;
    constexpr int LDS_B = BN + 4;
    static_assert((BM / TM) * (BN / TN) == 256, "256 threads");
    constexpr int NA = BM * BK / 1024;
    constexpr int NB = BN * BK / 1024;

    __shared__ float As[BK][LDS_A];
    __shared__ float Ws[BK][LDS_B];

    const int tid = threadIdx.x;
    constexpr int nx = BN / TN;
    const int tx = tid % nx, ty = tid / nx;
    const long row0 = (long)blockIdx.y * BM;
    const long col0 = (long)blockIdx.x * BN;

    float acc[TM][TN];
#pragma unroll
    for (int i = 0; i < TM; i++)
#pragma unroll
        for (int j = 0; j < TN; j++) acc[i][j] = 0.f;

    for (int kk = 0; kk < K; kk += BK) {
        float4 a_reg[NA], w_reg[NB];
#pragma unroll
        for (int i = 0; i < NA; ++i) {
            int idx = i * 1024 + tid * 4;
            int r = idx >> 4, k0 = idx & 15;
            int k = kk + k0;
            const float* p = A + (row0 + r) * (long)lda + k;
            a_reg[i] = *(const float4*)p;
        }
#pragma unroll
        for (int i = 0; i < NB; ++i) {
            int idx = i * 1024 + tid * 4;
            int r = idx >> 4, k0 = idx & 15;
            long gc = col0 + r;
            int k = kk + k0;
            if (gc < N) {
                const float* p = W + gc * (long)K + k;
                w_reg[i] = *(const float4*)p;
            } else w_reg[i] = make_float4(0.f, 0.f, 0.f, 0.f);
        }
        __syncthreads();
#pragma unroll
        for (int i = 0; i < NA; ++i) {
            int idx = i * 1024 + tid * 4;
            int r = idx >> 4, k0 = idx & 15;
            As[k0 + 0][r] = a_reg[i].x; As[k0 + 1][r] = a_reg[i].y;
            As[k0 + 2][r] = a_reg[i].z; As[k0 + 3][r] = a_reg[i].w;
        }
#pragma unroll
        for (int i = 0; i < NB; ++i) {
            int idx = i * 1024 + tid * 4;
            int r = idx >> 4, k0 = idx & 15;
            Ws[k0 + 0][r] = w_reg[i].x; Ws[k0 + 1][r] = w_reg[i].y;
            Ws[k0 + 2][r] = w_reg[i].z; Ws[k0 + 3][r] = w_reg[i].w;
        }
        __syncthreads();
#pragma unroll
        for (int k = 0; k < BK; ++k) {
            float a_f[TM], w_f[TN];
#pragma unroll
            for (int i = 0; i < TM; i += 4)
                *(float4*)&a_f[i] = *(const float4*)&As[k][ty * TM + i];
#pragma unroll
            for (int j = 0; j < TN; j += 4)
                *(float4*)&w_f[j] = *(const float4*)&Ws[k][tx * TN + j];
#pragma unroll
            for (int i = 0; i < TM; i++)
#pragma unroll
                for (int j = 0; j < TN; j++)
                    acc[i][j] = fmaf(a_f[i], w_f[j], acc[i][j]);
        }
    }
#pragma unroll
    for (int i = 0; i < TM; i++) {
        long r = row0 + ty * TM + i;
#pragma unroll
        for (int j = 0; j < TN; j++) {
            long c = col0 + tx * TN + j;
            if (c < N) C[r * ldc + c] = acc[i][j];
        }
    }
}

// ---------------------------------------------------------------------------
// causal depthwise conv (DC=4) + SiLU; 4 t per thread.
// out_t = cb + w3*x_t + w2*x_{t-1} + w1*x_{t-2} + w0*x_{t-3}
__global__ __launch_bounds__(256) void conv_silu_k(const float* __restrict__ xz,
                                                   const float* __restrict__ cw,
                                                   const float* __restrict__ cb,
                                                   float* __restrict__ xh)
{
    int c = threadIdx.x;       // 0..255
    int t0 = blockIdx.x << 2;  // 0,4,..252
    int bn = blockIdx.y;       // 0..127
    float w0 = cw[c * 4 + 0], w1 = cw[c * 4 + 1], w2 = cw[c * 4 + 2], w3 = cw[c * 4 + 3];
    float bb = cb[c];
    size_t base = ((size_t)bn * TT + t0) * 512 + c;
    float xm3 = (t0 >= 3) ? xz[base - 1536] : 0.f;
    float xm2 = (t0 >= 2) ? xz[base - 1024] : 0.f;
    float xm1 = (t0 >= 1) ? xz[base - 512]  : 0.f;
    float x0 = xz[base];
    float x1 = xz[base + 512];
    float x2 = xz[base + 1024];
    float x3 = xz[base + 1536];
    float o0 = bb + w3 * x0 + w2 * xm1 + w1 * xm2 + w0 * xm3;
    float o1 = bb + w3 * x1 + w2 * x0  + w1 * xm1 + w0 * xm2;
    float o2 = bb + w3 * x2 + w2 * x1  + w1 * x0  + w0 * xm1;
    float o3 = bb + w3 * x3 + w2 * x2  + w1 * x1  + w0 * x0;
    size_t ob = ((size_t)bn * TT + t0) * DI + c;
    xh[ob]           = o0 * sigm(o0);
    xh[ob + DI]      = o1 * sigm(o1);
    xh[ob + 2 * DI]  = o2 * sigm(o2);
    xh[ob + 3 * DI]  = o3 * sigm(o3);
}

// ---------------------------------------------------------------------------
// dt = softplus(xdbl[:, :8] @ dtw^T + dtb), written into xz[:, 0:256] (stride 512)
__global__ __launch_bounds__(256) void dt_k(const float* __restrict__ xdbl,
                                            const float* __restrict__ dtw,
                                            const float* __restrict__ dtb,
                                            float* __restrict__ dtout)
{
    int n = threadIdx.x;       // 0..255
    int tok = blockIdx.x;
    const float* xr = xdbl + (size_t)tok * 40;
    float acc = dtb[n];
#pragma unroll
    for (int k = 0; k < 8; k++) acc = fmaf(xr[k], dtw[n * 8 + k], acc);
    float sp = fmaxf(acc, 0.f) + __logf(1.f + __expf(-fabsf(acc)));
    dtout[(size_t)tok * 512 + n] = sp;
}

// ---------------------------------------------------------------------------
// selective scan, 8 states per thread, LDS double-buffered 16-step chunks.
// Thread = (bn, d, s-half); grid dim3(2, BN_), 256 threads.
// dt in xz[:,0:256]; z in xz[:,256:512]; xv in xh (aliases yg output).
#define SCH 16
__global__ __launch_bounds__(256) void scan_k(const float* __restrict__ xz,
                                              const float* xhp,         // aliases yg
                                              const float* __restrict__ xdbl,
                                              const float* __restrict__ A_log,
                                              const float* __restrict__ Dp,
                                              float* yg)
{
    __shared__ float sdt[2][SCH][128];
    __shared__ float sxv[2][SCH][128];
    __shared__ float szz[2][SCH][128];
    __shared__ float sbc[2][SCH][32];

    const int tid  = threadIdx.x;
    const int lane = tid & 63;
    const int wave = tid >> 6;
    const int sh   = lane >> 5;           // 0..1 (s-half)
    const int dloc = (wave << 5) + (lane & 31);   // 0..127
    const int bn   = blockIdx.y;
    const int dbase= blockIdx.x << 7;
    const int d    = dbase + dloc;
    const size_t tokb = (size_t)bn * TT;

    float A[8];
#pragma unroll
    for (int q = 0; q < 8; ++q)
        A[q] = -__expf(A_log[d * SS + sh * 8 + q]);
    const float Dv = Dp[d];

    float st[8];
#pragma unroll
    for (int q = 0; q < 8; ++q) st[q] = 0.f;

    // staging: 2 float4 per thread per stream + 1 for B/C (tid<128)
    const int st0 = tid >> 5,        sc0 = (tid & 31) << 2;          // steps 0..7
    const int st1 = (tid + 256) >> 5, sc1 = (tid & 31) << 2;         // steps 8..15
    const int bstep = tid >> 3, bq = (tid & 7) << 2;                 // B/C
    float4 rdt[2], rxv[2], rz[2], rbc;

#define STAGE_ISSUE(TB) do {                                              \
    size_t tb_ = tokb + (TB);                                             \
    rdt[0] = *(const float4*)&xz [(tb_ + st0) * 512 + dbase + sc0];       \
    rdt[1] = *(const float4*)&xz [(tb_ + st1) * 512 + dbase + sc1];       \
    rxv[0] = *(const float4*)&xhp[(tb_ + st0) * DI  + dbase + sc0];       \
    rxv[1] = *(const float4*)&xhp[(tb_ + st1) * DI  + dbase + sc1];       \
    rz [0] = *(const float4*)&xz [(tb_ + st0) * 512 + 256 + dbase + sc0]; \
    rz [1] = *(const float4*)&xz [(tb_ + st1) * 512 + 256 + dbase + sc1]; \
    if (tid < 128) rbc = *(const float4*)&xdbl[(tb_ + bstep) * 40 + 8 + bq]; \
} while (0)

#define STAGE_WRITE(B) do {                                               \
    *(float4*)&sdt[B][st0][sc0] = rdt[0];                                 \
    *(float4*)&sdt[B][st1][sc1] = rdt[1];                                 \
    *(float4*)&sxv[B][st0][sc0] = rxv[0];                                 \
    *(float4*)&sxv[B][st1][sc1] = rxv[1];                                 \
    *(float4*)&szz[B][st0][sc0] = rz[0];                                  \
    *(float4*)&szz[B][st1][sc1] = rz[1];                                  \
    if (tid < 128) *(float4*)&sbc[B][bstep][bq] = rbc;                    \
} while (0)

    STAGE_ISSUE(0);
    STAGE_WRITE(0);
    __syncthreads();

    for (int c = 0; c < TT / SCH; ++c) {
        const int b = c & 1;
        if (c + 1 < TT / SCH) STAGE_ISSUE((c + 1) * SCH);
        const int tb = c * SCH;
#pragma unroll
        for (int s = 0; s < SCH; ++s) {
            float dt_c = sdt[b][s][dloc];
            float xv_c = sxv[b][s][dloc];
            float z_c  = szz[b][s][dloc];
            float4 B0c = *(const float4*)&sbc[b][s][sh * 8];
            float4 B1c = *(const float4*)&sbc[b][s][sh * 8 + 4];
            float4 C0c = *(const float4*)&sbc[b][s][16 + sh * 8];
            float4 C1c = *(const float4*)&sbc[b][s][16 + sh * 8 + 4];

            float dtx = dt_c * xv_c;
            float dA0 = __expf(A[0] * dt_c);
            float dA1 = __expf(A[1] * dt_c);
            float dA2 = __expf(A[2] * dt_c);
            float dA3 = __expf(A[3] * dt_c);
            float dA4 = __expf(A[4] * dt_c);
            float dA5 = __expf(A[5] * dt_c);
            float dA6 = __expf(A[6] * dt_c);
            float dA7 = __expf(A[7] * dt_c);
            st[0] = fmaf(dA0, st[0], dtx * B0c.x);
            st[1] = fmaf(dA1, st[1], dtx * B0c.y);
            st[2] = fmaf(dA2, st[2], dtx * B0c.z);
            st[3] = fmaf(dA3, st[3], dtx * B0c.w);
            st[4] = fmaf(dA4, st[4], dtx * B1c.x);
            st[5] = fmaf(dA5, st[5], dtx * B1c.y);
            st[6] = fmaf(dA6, st[6], dtx * B1c.z);
            st[7] = fmaf(dA7, st[7], dtx * B1c.w);
            float y0 = st[0] * C0c.x;
            float y1 = st[1] * C0c.y;
            y0 = fmaf(st[2], C0c.z, y0);
            y1 = fmaf(st[3], C0c.w, y1);
            y0 = fmaf(st[4], C1c.x, y0);
            y1 = fmaf(st[5], C1c.y, y1);
            y0 = fmaf(st[6], C1c.z, y0);
            y1 = fmaf(st[7], C1c.w, y1);
            float y = y0 + y1;
            y += __shfl_xor(y, 32, 64);
            float zg = __fdividef(z_c, 1.f + __expf(-z_c));
            float outv = (y + Dv * xv_c) * zg;
            if (sh == 0) yg[(tokb + tb + s) * DI + d] = outv;
        }
        if (c + 1 < TT / SCH) STAGE_WRITE(b ^ 1);
        __syncthreads();
    }
#undef STAGE_ISSUE
#undef STAGE_WRITE
}

// ---------------------------------------------------------------------------
// per-token small projections on fused buffer (stride 512); 4 tokens/block
__global__ __launch_bounds__(256) void gate_k(const float* __restrict__ gmb,
                                              const float* __restrict__ gw2,
                                              const float* __restrict__ gb2,
                                              const float* __restrict__ mw2,
                                              const float* __restrict__ mb2,
                                              const float* __restrict__ Ascale,
                                              float* __restrict__ ws4,
                                              float* __restrict__ dts,
                                              float* __restrict__ gs)
{
    int l = threadIdx.x & 63;
    int tok = blockIdx.x * 4 + (threadIdx.x >> 6);
    const float* g1 = gmb + (size_t)tok * 512;
    float a0 = g1[l], a1 = g1[l + 64];
    float m0 = g1[128 + l], m1v = g1[192 + l];
    float p[5];
#pragma unroll
    for (int j = 0; j < 5; j++)
        p[j] = a0 * gw2[j * DM + l] + a1 * gw2[j * DM + l + 64];
    float q = m0 * mw2[l] + m1v * mw2[l + 64];
#pragma unroll
    for (int off = 32; off; off >>= 1) {
#pragma unroll
        for (int j = 0; j < 5; j++) p[j] += __shfl_xor(p[j], off, 64);
        q += __shfl_xor(q, off, 64);
    }
    if (l == 0) {
        float go[5];
#pragma unroll
        for (int j = 0; j < 5; j++) go[j] = p[j] + gb2[j];
        float mx = fmaxf(fmaxf(go[0], go[1]), fmaxf(go[2], go[3]));
        float e[4], sum = 0.f;
#pragma unroll
        for (int k = 0; k < 4; k++) { e[k] = expf(go[k] - mx); sum += e[k]; }
        float inv = 1.f / sum;
#pragma unroll
        for (int k = 0; k < 4; k++) ws4[(size_t)tok * 4 + k] = e[k] * inv * Ascale[k];
        dts[tok] = 0.2f * sigm(go[4]);
        gs[tok]  = sigm(q + mb2[0]);
    }
}

// ---------------------------------------------------------------------------
// pack Wu[kr][d] = U[k][d][r], Wv[d][kr] = V[k][r][d]  (both 8192 elems)
__global__ __launch_bounds__(256) void pack_uv_k(const float* __restrict__ U,
                                                 const float* __restrict__ V,
                                                 float* __restrict__ Wu,
                                                 float* __restrict__ Wv)
{
    int i = blockIdx.x * 256 + threadIdx.x;
    if (i < 8192) {
        int kr = i >> 7, d = i & 127;
        int k = kr >> 4, r = kr & 15;
        Wu[i] = U[((size_t)k * DM + d) * RR + r];
        int d2 = i >> 6, kr2 = i & 63;
        int k2 = kr2 >> 4, r2 = kr2 & 15;
        Wv[i] = V[((size_t)k2 * RR + r2) * DM + d2];
    }
}

// ---------------------------------------------------------------------------
// pack Wcat (512x128) = [gw1; mw1; fgw; fbw], bcat(512)
__global__ __launch_bounds__(256) void pack_cat_k(const float* __restrict__ gw1,
                                                  const float* __restrict__ gb1,
                                                  const float* __restrict__ mw1,
                                                  const float* __restrict__ mb1,
                                                  const float* __restrict__ fgw,
                                                  const float* __restrict__ fgb,
                                                  const float* __restrict__ fbw,
                                                  const float* __restrict__ fbb,
                                                  float* __restrict__ Wcat,
                                                  float* __restrict__ bcat)
{
    int i = blockIdx.x * 256 + threadIdx.x;
    if (i < 65536) {
        int r = i >> 7, k = i & 127;
        int sel = r >> 7;
        int rr = r & 127;
        const float* src = (sel == 0) ? gw1 : (sel == 1) ? mw1 : (sel == 2) ? fgw : fbw;
        Wcat[i] = src[rr * DM + k];
    }
    if (i < 512) {
        int sel = i >> 7, rr = i & 127;
        const float* src = (sel == 0) ? gb1 : (sel == 1) ? mb1 : (sel == 2) ? fgb : fbb;
        bcat[i] = src[rr];
    }
}

// ---------------------------------------------------------------------------
// final combine + transpose back to (B,T,N,D); 2 tokens/block
__global__ __launch_bounds__(256) void combine_k(const float* __restrict__ h,
                                                 const float* __restrict__ hA,
                                                 const float* __restrict__ hA2,
                                                 const float* __restrict__ gmb,
                                                 const float* __restrict__ dts,
                                                 const float* __restrict__ gs,
                                                 float* __restrict__ out)
{
    int tid = threadIdx.x;
    int d = tid & 127;
    int tok = blockIdx.x * 2 + (tid >> 7);
    int t = tok & 255;
    int bn = tok >> 8;
    int b = bn >> 5, n = bn & 31;
    float dtv = dts[tok], gv = gs[tok];
    size_t i = (size_t)tok * DM + d;
    float u = tanhf(dtv * hA[i] + 0.5f * dtv * dtv * hA2[i]);
    float gamma = gmb[(size_t)tok * 512 + 256 + d];
    float beta  = gmb[(size_t)tok * 512 + 384 + d];
    u = gamma * u + beta;
    out[(((size_t)b * TT + t) * NN + n) * DM + d] = h[i] + gv * u;
}

// ---------------------------------------------------------------------------
extern "C" void kernel_launch(void* const* d_in, const int* in_sizes, int n_in,
                              void* d_out, int out_size, void* d_ws, size_t ws_size,
                              hipStream_t stream)
{
    const float* x       = (const float*)d_in[0];
    const float* in_w    = (const float*)d_in[1];   // (2,512,128)
    const float* conv_w  = (const float*)d_in[2];   // (2,256,4)
    const float* conv_b  = (const float*)d_in[3];   // (2,256)
    const float* xpw     = (const float*)d_in[4];   // (2,40,256)
    const float* dtw     = (const float*)d_in[5];   // (2,256,8)
    const float* dtb     = (const float*)d_in[6];   // (2,256)
    const float* A_log   = (const float*)d_in[7];   // (2,256,16)
    const float* D_skip  = (const float*)d_in[8];   // (2,256)
    const float* ow      = (const float*)d_in[9];   // (2,128,256)
    const float* U       = (const float*)d_in[10];  // (4,128,16)
    const float* V       = (const float*)d_in[11];  // (4,16,128)
    const float* Ascale  = (const float*)d_in[12];  // (4)
    const float* gw1     = (const float*)d_in[13];
    const float* gb1     = (const float*)d_in[14];
    const float* gw2     = (const float*)d_in[15];
    const float* gb2     = (const float*)d_in[16];
    const float* fgw     = (const float*)d_in[17];
    const float* fgb     = (const float*)d_in[18];
    const float* fbw     = (const float*)d_in[19];
    const float* fbb     = (const float*)d_in[20];
    const float* mw1     = (const float*)d_in[21];
    const float* mb1     = (const float*)d_in[22];
    const float* mw2     = (const float*)d_in[23];
    const float* mb2     = (const float*)d_in[24];

    float* ws = (float*)d_ws;
    float* h    = ws;                       //  4,194,304 floats
    float* xz   = h + 4194304;              // 16,777,216 (dt cols 0..255; final: gmb)
    float* xh   = xz + 16777216;            //  8,388,608 (final: hA, hA2)
    float* xdbl = xh + 8388608;             //  1,310,720 (final: Wcat/bcat/Wu/Wv/ws4/dts/gs)
    // total 30,670,848 floats = 122.7 MB

    pack_h_k<<<TOK / 2, 256, 0, stream>>>(x, h);

    for (int l = 0; l < LL; ++l) {
        const float* iw = in_w + (size_t)l * 512 * 128;
        mgemm_k<0,0><<<dim3(8,256), 256, 0, stream>>>(
            h, DM, iw, nullptr, xz, 512, 512, 128, nullptr, 0);
        conv_silu_k<<<dim3(TT / 4, BN_), 256, 0, stream>>>(
            xz, conv_w + (size_t)l * DI * DCV, conv_b + (size_t)l * DI, xh);
        gemm_k<64,64,4,4,0><<<dim3(1,512), 256, 0, stream>>>(
            xh, DI, xpw + (size_t)l * 40 * DI, nullptr, xdbl, 40, TOK, 40, DI, nullptr);
        dt_k<<<TOK, 256, 0, stream>>>(
            xdbl, dtw + (size_t)l * DI * DTR, dtb + (size_t)l * DI, xz);
        scan_k<<<dim3(2, BN_), 256, 0, stream>>>(
            xz, xh, xdbl, A_log + (size_t)l * DI * SS, D_skip + (size_t)l * DI, xh);
        mgemm_k<4,0><<<dim3(2,256), 256, 0, stream>>>(
            xh, DI, ow + (size_t)l * DM * DI, nullptr, h, DM, 128, 256, nullptr, 0);
    }

    // ---------------- final stage ----------------
    float* gmb  = xz;
    float* Zb   = xz;                       // cols 0..63, stride 512
    float* hA   = xh;
    float* hA2  = xh + 4194304;
    float* Wcat = xdbl;                     // 65,536
    float* bcat = xdbl + 65536;             // 512
    float* Wu   = xdbl + 66048;             // 8,192
    float* Wv   = xdbl + 74240;             // 8,192
    float* ws4  = xdbl + 82432;             // TOK*4
    float* dts  = xdbl + 213504;            // TOK
    float* gs   = xdbl + 246272;            // TOK

    pack_cat_k<<<256, 256, 0, stream>>>(gw1, gb1, mw1, mb1, fgw, fgb, fbw, fbb, Wcat, bcat);
    mgemm_k<1,1><<<dim3(4,256), 256, 0, stream>>>(
        h, DM, Wcat, bcat, gmb, 512, 256, 128, nullptr, 0);
    mgemm_k<1,2><<<dim3(4,256), 256, 0, stream>>>(
        h, DM, Wcat + 256 * 128, bcat + 256, gmb + 256, 512, 256, 128, nullptr, 0);
    gate_k<<<TOK / 4, 256, 0, stream>>>(gmb, gw2, gb2, mw2, mb2, Ascale, ws4, dts, gs);
    pack_uv_k<<<32, 256, 0, stream>>>(U, V, Wu, Wv);

    mgemm_k<6,0><<<dim3(1,256), 256, 0, stream>>>(
        h, DM, Wu, nullptr, Zb, 512, 64, 128, ws4, 0);
    mgemm_k<0,0><<<dim3(2,256), 256, 0, stream>>>(
        Zb, 512, Wv, nullptr, hA, DM, 128, 64, nullptr, 0);
    mgemm_k<6,0><<<dim3(1,256), 256, 0, stream>>>(
        hA, DM, Wu, nullptr, Zb, 512, 64, 128, ws4, 0);
    mgemm_k<0,0><<<dim3(2,256), 256, 0, stream>>>(
        Zb, 512, Wv, nullptr, hA2, DM, 128, 64, nullptr, 0);

    combine_k<<<TOK / 2, 256, 0, stream>>>(h, hA, hA2, gmb, dts, gs, (float*)d_out);
}

// Round 6
// 543.939 us; speedup vs baseline: 2.3411x; 1.0740x over previous
//
#include <hip/hip_runtime.h>
#include <math.h>

// Problem constants
#define BSZ   4
#define TT    256
#define NN    32
#define DM    128
#define LL    2
#define SS    16
#define DCV   4
#define DI    256
#define DTR   8
#define KK    4
#define RR    16
#define BN_   128          // BSZ*NN
#define TOK   32768        // BN_*TT

typedef _Float16 f16x8 __attribute__((ext_vector_type(8)));
typedef float    f32x4 __attribute__((ext_vector_type(4)));

__device__ __forceinline__ float sigm(float x) { return __fdividef(1.f, 1.f + __expf(-x)); }

// ---------------------------------------------------------------------------
// pack x (B,T,N,D) -> h (BN,T,D)
__global__ __launch_bounds__(256) void pack_h_k(const float* __restrict__ x, float* __restrict__ h)
{
    int tid = threadIdx.x;
    int d = tid & 127;
    int tok = blockIdx.x * 2 + (tid >> 7);
    int t = tok & 255;
    int bn = tok >> 8;
    int b = bn >> 5, n = bn & 31;
    h[(size_t)tok * DM + d] = x[(((size_t)b * TT + t) * NN + n) * DM + d];
}

// ---------------------------------------------------------------------------
// MFMA f16 GEMM: C[M,N] = A[M,K] @ W[N,K]^T (+epilogue), fp32 I/O, f16 compute
// Tile 128 (M) x 64 (N), 4 waves, K-chunks of 32, LDS double-buffered.
// EPI: 0 store, 1 +bias(+ACT), 4 C += v, 6 v *= aux[row*4 + (col>>4)+auxb]
// ACT: 0 none, 1 gelu, 2 tanh  (uniform per dispatch)
template<int EPI, int ACT>
__global__ __launch_bounds__(256)
void mgemm_k(const float* __restrict__ A, int lda,
             const float* __restrict__ W,
             const float* __restrict__ bias,
             float* C, int ldc,
             int N, int K,
             const float* __restrict__ aux, int auxb)
{
    __shared__ char smem[24576];

    const int tid  = threadIdx.x;
    const int lane = tid & 63;
    const int wv   = tid >> 6;            // 0..3
    const long row0 = (long)blockIdx.y * 128;
    const int  colb = blockIdx.x * 64;    // dispatch-local col base
    const int  NC   = K >> 5;             // 32-k chunks

    const int st_rc = tid >> 2;           // 0..63
    const int st_g  = tid & 3;
    const int offA0 = st_rc * 64        + ((st_g ^ (st_rc & 3)) << 4);
    const int offA1 = (st_rc + 64) * 64 + ((st_g ^ (st_rc & 3)) << 4);
    const int offW  = st_rc * 64        + ((st_g ^ (st_rc & 3)) << 4);
    const int wcol  = colb + st_rc;
    const bool wok  = (wcol < N);

    const int fr = lane & 15;
    const int fg = lane >> 4;
    const int ra0 = (wv << 5) + fr;
    const int offa0 = ra0 * 64        + ((fg ^ (ra0 & 3)) << 4);
    const int offa1 = (ra0 + 16) * 64 + ((fg ^ (ra0 & 3)) << 4);
    int offb[4];
#pragma unroll
    for (int nj = 0; nj < 4; ++nj) {
        int cb = (nj << 4) + fr;
        offb[nj] = cb * 64 + ((fg ^ (fr & 3)) << 4);
    }

    f32x4 acc[2][4];
#pragma unroll
    for (int mi = 0; mi < 2; ++mi)
#pragma unroll
        for (int nj = 0; nj < 4; ++nj) acc[mi][nj] = (f32x4){0.f, 0.f, 0.f, 0.f};

    float va0[8], va1[8], vw[8];

    {
        const float* pa0 = A + (row0 + st_rc) * (long)lda + st_g * 8;
        *(float4*)&va0[0] = *(const float4*)pa0;
        *(float4*)&va0[4] = *(const float4*)(pa0 + 4);
        const float* pa1 = pa0 + 64 * (long)lda;
        *(float4*)&va1[0] = *(const float4*)pa1;
        *(float4*)&va1[4] = *(const float4*)(pa1 + 4);
        if (wok) {
            const float* pw = W + (long)wcol * K + st_g * 8;
            *(float4*)&vw[0] = *(const float4*)pw;
            *(float4*)&vw[4] = *(const float4*)(pw + 4);
        } else {
#pragma unroll
            for (int j = 0; j < 8; ++j) vw[j] = 0.f;
        }
    }
    {
        char* base = smem;
        f16x8 h0, h1, hw;
#pragma unroll
        for (int j = 0; j < 8; ++j) { h0[j] = (_Float16)va0[j]; h1[j] = (_Float16)va1[j]; hw[j] = (_Float16)vw[j]; }
        *(f16x8*)(base + offA0) = h0;
        *(f16x8*)(base + offA1) = h1;
        *(f16x8*)(base + 8192 + offW) = hw;
    }
    __syncthreads();

    for (int c = 0; c < NC; ++c) {
        if (c + 1 < NC) {
            const int kk = (c + 1) << 5;
            const float* pa0 = A + (row0 + st_rc) * (long)lda + kk + st_g * 8;
            *(float4*)&va0[0] = *(const float4*)pa0;
            *(float4*)&va0[4] = *(const float4*)(pa0 + 4);
            const float* pa1 = pa0 + 64 * (long)lda;
            *(float4*)&va1[0] = *(const float4*)pa1;
            *(float4*)&va1[4] = *(const float4*)(pa1 + 4);
            if (wok) {
                const float* pw = W + (long)wcol * K + kk + st_g * 8;
                *(float4*)&vw[0] = *(const float4*)pw;
                *(float4*)&vw[4] = *(const float4*)(pw + 4);
            }
        }
        {
            const char* As = smem + (c & 1) * 12288;
            const char* Ws = As + 8192;
            f16x8 af0 = *(const f16x8*)(As + offa0);
            f16x8 af1 = *(const f16x8*)(As + offa1);
            f16x8 bf[4];
#pragma unroll
            for (int nj = 0; nj < 4; ++nj) bf[nj] = *(const f16x8*)(Ws + offb[nj]);
#pragma unroll
            for (int nj = 0; nj < 4; ++nj) {
                acc[0][nj] = __builtin_amdgcn_mfma_f32_16x16x32_f16(af0, bf[nj], acc[0][nj], 0, 0, 0);
                acc[1][nj] = __builtin_amdgcn_mfma_f32_16x16x32_f16(af1, bf[nj], acc[1][nj], 0, 0, 0);
            }
        }
        if (c + 1 < NC) {
            char* base = smem + ((c + 1) & 1) * 12288;
            f16x8 h0, h1, hw;
#pragma unroll
            for (int j = 0; j < 8; ++j) { h0[j] = (_Float16)va0[j]; h1[j] = (_Float16)va1[j]; hw[j] = (_Float16)vw[j]; }
            *(f16x8*)(base + offA0) = h0;
            *(f16x8*)(base + offA1) = h1;
            *(f16x8*)(base + 8192 + offW) = hw;
        }
        __syncthreads();
    }

#pragma unroll
    for (int nj = 0; nj < 4; ++nj) {
        int col = colb + (nj << 4) + fr;
        if (col < N) {
            float bb = 0.f;
            if (EPI == 1 && bias) bb = bias[col];
#pragma unroll
            for (int mi = 0; mi < 2; ++mi) {
                long rg = row0 + (wv << 5) + (mi << 4) + (fg << 2);
#pragma unroll
                for (int r = 0; r < 4; ++r) {
                    float v = acc[mi][nj][r];
                    if (EPI == 1) {
                        v += bb;
                        if (ACT == 1) v = 0.5f * v * (1.f + erff(v * 0.70710678118654752f));
                        else if (ACT == 2) v = tanhf(v);
                    } else if (EPI == 6) {
                        v *= aux[(rg + r) * 4 + ((col >> 4) + auxb)];
                    }
                    float* pc = C + (rg + r) * (long)ldc + col;
                    if (EPI == 4) *pc += v;
                    else          *pc = v;
                }
            }
        }
    }
}

// ---------------------------------------------------------------------------
// fp32 tiled GEMM (kept for the precision-sensitive x_dbl projection)
template<int BM, int BN, int TM, int TN, int EPI>
__global__ __launch_bounds__(256)
void gemm_k(const float* __restrict__ A, int lda,
            const float* __restrict__ W,
            const float* __restrict__ bias,
            float* C, int ldc,
            int M, int N, int K,
            const float* __restrict__ aux)
{
    constexpr int BK = 16;
    constexpr int LDS_A = BM + 4;
    constexpr int LDS_B = BN + 4;
    static_assert((BM / TM) * (BN / TN) == 256, "256 threads");
    constexpr int NA = BM * BK / 1024;
    constexpr int NB = BN * BK / 1024;

    __shared__ float As[BK][LDS_A];
    __shared__ float Ws[BK][LDS_B];

    const int tid = threadIdx.x;
    constexpr int nx = BN / TN;
    const int tx = tid % nx, ty = tid / nx;
    const long row0 = (long)blockIdx.y * BM;
    const long col0 = (long)blockIdx.x * BN;

    float acc[TM][TN];
#pragma unroll
    for (int i = 0; i < TM; i++)
#pragma unroll
        for (int j = 0; j < TN; j++) acc[i][j] = 0.f;

    for (int kk = 0; kk < K; kk += BK) {
        float4 a_reg[NA], w_reg[NB];
#pragma unroll
        for (int i = 0; i < NA; ++i) {
            int idx = i * 1024 + tid * 4;
            int r = idx >> 4, k0 = idx & 15;
            int k = kk + k0;
            const float* p = A + (row0 + r) * (long)lda + k;
            a_reg[i] = *(const float4*)p;
        }
#pragma unroll
        for (int i = 0; i < NB; ++i) {
            int idx = i * 1024 + tid * 4;
            int r = idx >> 4, k0 = idx & 15;
            long gc = col0 + r;
            int k = kk + k0;
            if (gc < N) {
                const float* p = W + gc * (long)K + k;
                w_reg[i] = *(const float4*)p;
            } else w_reg[i] = make_float4(0.f, 0.f, 0.f, 0.f);
        }
        __syncthreads();
#pragma unroll
        for (int i = 0; i < NA; ++i) {
            int idx = i * 1024 + tid * 4;
            int r = idx >> 4, k0 = idx & 15;
            As[k0 + 0][r] = a_reg[i].x; As[k0 + 1][r] = a_reg[i].y;
            As[k0 + 2][r] = a_reg[i].z; As[k0 + 3][r] = a_reg[i].w;
        }
#pragma unroll
        for (int i = 0; i < NB; ++i) {
            int idx = i * 1024 + tid * 4;
            int r = idx >> 4, k0 = idx & 15;
            Ws[k0 + 0][r] = w_reg[i].x; Ws[k0 + 1][r] = w_reg[i].y;
            Ws[k0 + 2][r] = w_reg[i].z; Ws[k0 + 3][r] = w_reg[i].w;
        }
        __syncthreads();
#pragma unroll
        for (int k = 0; k < BK; ++k) {
            float a_f[TM], w_f[TN];
#pragma unroll
            for (int i = 0; i < TM; i += 4)
                *(float4*)&a_f[i] = *(const float4*)&As[k][ty * TM + i];
#pragma unroll
            for (int j = 0; j < TN; j += 4)
                *(float4*)&w_f[j] = *(const float4*)&Ws[k][tx * TN + j];
#pragma unroll
            for (int i = 0; i < TM; i++)
#pragma unroll
                for (int j = 0; j < TN; j++)
                    acc[i][j] = fmaf(a_f[i], w_f[j], acc[i][j]);
        }
    }
#pragma unroll
    for (int i = 0; i < TM; i++) {
        long r = row0 + ty * TM + i;
#pragma unroll
        for (int j = 0; j < TN; j++) {
            long c = col0 + tx * TN + j;
            if (c < N) C[r * ldc + c] = acc[i][j];
        }
    }
}

// ---------------------------------------------------------------------------
// causal depthwise conv (DC=4) + SiLU; 4 t per thread.
__global__ __launch_bounds__(256) void conv_silu_k(const float* __restrict__ xz,
                                                   const float* __restrict__ cw,
                                                   const float* __restrict__ cb,
                                                   float* __restrict__ xh)
{
    int c = threadIdx.x;       // 0..255
    int t0 = blockIdx.x << 2;  // 0,4,..252
    int bn = blockIdx.y;       // 0..127
    float w0 = cw[c * 4 + 0], w1 = cw[c * 4 + 1], w2 = cw[c * 4 + 2], w3 = cw[c * 4 + 3];
    float bb = cb[c];
    size_t base = ((size_t)bn * TT + t0) * 512 + c;
    float xm3 = (t0 >= 3) ? xz[base - 1536] : 0.f;
    float xm2 = (t0 >= 2) ? xz[base - 1024] : 0.f;
    float xm1 = (t0 >= 1) ? xz[base - 512]  : 0.f;
    float x0 = xz[base];
    float x1 = xz[base + 512];
    float x2 = xz[base + 1024];
    float x3 = xz[base + 1536];
    float o0 = bb + w3 * x0 + w2 * xm1 + w1 * xm2 + w0 * xm3;
    float o1 = bb + w3 * x1 + w2 * x0  + w1 * xm1 + w0 * xm2;
    float o2 = bb + w3 * x2 + w2 * x1  + w1 * x0  + w0 * xm1;
    float o3 = bb + w3 * x3 + w2 * x2  + w1 * x1  + w0 * x0;
    size_t ob = ((size_t)bn * TT + t0) * DI + c;
    xh[ob]           = o0 * sigm(o0);
    xh[ob + DI]      = o1 * sigm(o1);
    xh[ob + 2 * DI]  = o2 * sigm(o2);
    xh[ob + 3 * DI]  = o3 * sigm(o3);
}

// ---------------------------------------------------------------------------
// selective scan v3: 4 states/thread, 512 threads (8 waves), dt fused in.
// Thread: d = dbase + (wave<<4)+(lane&15), sq = lane>>4 (s-quad).
// LDS double-buffered 16-step chunks; dt computed in-kernel from xdbl[:,0:8].
// z in xz[:,256:512]; xv in xh (aliases yg output); B/C + dt-in from xdbl.
#define SCH 16
__global__ __launch_bounds__(512) void scan_k(const float* __restrict__ xz,
                                              const float* xhp,         // aliases yg
                                              const float* __restrict__ xdbl,
                                              const float* __restrict__ dtw,
                                              const float* __restrict__ dtb,
                                              const float* __restrict__ A_log,
                                              const float* __restrict__ Dp,
                                              float* yg)
{
    __shared__ float sdt[2][SCH][128];
    __shared__ float sxv[2][SCH][128];
    __shared__ float szz[2][SCH][128];
    __shared__ float sbc[2][SCH][32];
    __shared__ float sxd[2][SCH][8];

    const int tid  = threadIdx.x;         // 0..511
    const int lane = tid & 63;
    const int wave = tid >> 6;            // 0..7
    const int sq   = lane >> 4;           // 0..3 (s-quad)
    const int dloc = (wave << 4) + (lane & 15);   // 0..127
    const int bn   = blockIdx.y;
    const int dbase= blockIdx.x << 7;
    const int d    = dbase + dloc;
    const size_t tokb = (size_t)bn * TT;

    float A[4];
#pragma unroll
    for (int q = 0; q < 4; ++q)
        A[q] = -__expf(A_log[d * SS + sq * 4 + q]);
    const float Dv = Dp[d];

    float st[4];
#pragma unroll
    for (int q = 0; q < 4; ++q) st[q] = 0.f;

    // --- staging roles ---
    const int st0 = tid >> 5;                   // 0..15 (step row)
    const int sc0 = (tid & 31) << 2;            // 0..124 (d col, float4)
    const int bstep = tid >> 3, bq = (tid & 7) << 2;   // B/C (tid<128)
    const int xi = tid - 128;                   // xdbl dt-cols (tid 128..159)
    const int xr = xi >> 1, xc4 = (xi & 1) << 2;
    float4 rxv, rzz, rbc, rxd;

    // --- dt compute role: s = tid>>5, 4 consecutive d ---
    const int dt_s  = tid >> 5;                 // 0..15
    const int dt_d4 = (tid & 31) << 2;          // 0..124
    float dtwv[4][8];
    float dtbv[4];
#pragma unroll
    for (int j = 0; j < 4; ++j) {
        const float* p = dtw + (size_t)(dbase + dt_d4 + j) * 8;
        *(float4*)&dtwv[j][0] = *(const float4*)p;
        *(float4*)&dtwv[j][4] = *(const float4*)(p + 4);
        dtbv[j] = dtb[dbase + dt_d4 + j];
    }

#define STAGE_ISSUE(TB) do {                                              \
    size_t tb_ = tokb + (TB);                                             \
    rxv = *(const float4*)&xhp[(tb_ + st0) * DI + dbase + sc0];           \
    rzz = *(const float4*)&xz [(tb_ + st0) * 512 + 256 + dbase + sc0];    \
    if (tid < 128) rbc = *(const float4*)&xdbl[(tb_ + bstep) * 40 + 8 + bq]; \
    else if (tid < 160) rxd = *(const float4*)&xdbl[(tb_ + xr) * 40 + xc4]; \
} while (0)

#define STAGE_WRITE(B) do {                                               \
    *(float4*)&sxv[B][st0][sc0] = rxv;                                    \
    *(float4*)&szz[B][st0][sc0] = rzz;                                    \
    if (tid < 128) *(float4*)&sbc[B][bstep][bq] = rbc;                    \
    else if (tid < 160) *(float4*)&sxd[B][xr][xc4] = rxd;                 \
} while (0)

#define DT_COMPUTE(B) do {                                                \
    float4 o_;                                                            \
    _Pragma("unroll")                                                     \
    for (int j = 0; j < 4; ++j) {                                         \
        float v_ = dtbv[j];                                               \
        _Pragma("unroll")                                                 \
        for (int k = 0; k < 8; ++k)                                       \
            v_ = fmaf(sxd[B][dt_s][k], dtwv[j][k], v_);                   \
        o_[j] = fmaxf(v_, 0.f) + __logf(1.f + __expf(-fabsf(v_)));        \
    }                                                                     \
    *(float4*)&sdt[B][dt_s][dt_d4] = o_;                                  \
} while (0)

    STAGE_ISSUE(0);
    STAGE_WRITE(0);
    __syncthreads();
    DT_COMPUTE(0);
    __syncthreads();

    for (int c = 0; c < TT / SCH; ++c) {
        const int b = c & 1;
        const bool more = (c + 1 < TT / SCH);
        if (more) STAGE_ISSUE((c + 1) * SCH);
        const int tb = c * SCH;
#pragma unroll
        for (int s = 0; s < SCH; ++s) {
            float dt_c = sdt[b][s][dloc];
            float xv_c = sxv[b][s][dloc];
            float z_c  = szz[b][s][dloc];
            float4 B4 = *(const float4*)&sbc[b][s][sq << 2];
            float4 C4 = *(const float4*)&sbc[b][s][16 + (sq << 2)];

            float dtx = dt_c * xv_c;
            float dA0 = __expf(A[0] * dt_c);
            float dA1 = __expf(A[1] * dt_c);
            float dA2 = __expf(A[2] * dt_c);
            float dA3 = __expf(A[3] * dt_c);
            st[0] = fmaf(dA0, st[0], dtx * B4.x);
            st[1] = fmaf(dA1, st[1], dtx * B4.y);
            st[2] = fmaf(dA2, st[2], dtx * B4.z);
            st[3] = fmaf(dA3, st[3], dtx * B4.w);
            float y0 = st[0] * C4.x;
            float y1 = st[1] * C4.y;
            y0 = fmaf(st[2], C4.z, y0);
            y1 = fmaf(st[3], C4.w, y1);
            float y = y0 + y1;
            y += __shfl_xor(y, 16, 64);
            y += __shfl_xor(y, 32, 64);
            float zg = __fdividef(z_c, 1.f + __expf(-z_c));
            float outv = (y + Dv * xv_c) * zg;
            if (sq == 0) yg[(tokb + tb + s) * DI + d] = outv;
        }
        if (more) STAGE_WRITE(b ^ 1);
        __syncthreads();
        if (more) DT_COMPUTE(b ^ 1);
        __syncthreads();
    }
#undef STAGE_ISSUE
#undef STAGE_WRITE
#undef DT_COMPUTE
}

// ---------------------------------------------------------------------------
// per-token small projections on fused buffer (stride 512); 4 tokens/block
__global__ __launch_bounds__(256) void gate_k(const float* __restrict__ gmb,
                                              const float* __restrict__ gw2,
                                              const float* __restrict__ gb2,
                                              const float* __restrict__ mw2,
                                              const float* __restrict__ mb2,
                                              const float* __restrict__ Ascale,
                                              float* __restrict__ ws4,
                                              float* __restrict__ dts,
                                              float* __restrict__ gs)
{
    int l = threadIdx.x & 63;
    int tok = blockIdx.x * 4 + (threadIdx.x >> 6);
    const float* g1 = gmb + (size_t)tok * 512;
    float a0 = g1[l], a1 = g1[l + 64];
    float m0 = g1[128 + l], m1v = g1[192 + l];
    float p[5];
#pragma unroll
    for (int j = 0; j < 5; j++)
        p[j] = a0 * gw2[j * DM + l] + a1 * gw2[j * DM + l + 64];
    float q = m0 * mw2[l] + m1v * mw2[l + 64];
#pragma unroll
    for (int off = 32; off; off >>= 1) {
#pragma unroll
        for (int j = 0; j < 5; j++) p[j] += __shfl_xor(p[j], off, 64);
        q += __shfl_xor(q, off, 64);
    }
    if (l == 0) {
        float go[5];
#pragma unroll
        for (int j = 0; j < 5; j++) go[j] = p[j] + gb2[j];
        float mx = fmaxf(fmaxf(go[0], go[1]), fmaxf(go[2], go[3]));
        float e[4], sum = 0.f;
#pragma unroll
        for (int k = 0; k < 4; k++) { e[k] = expf(go[k] - mx); sum += e[k]; }
        float inv = 1.f / sum;
#pragma unroll
        for (int k = 0; k < 4; k++) ws4[(size_t)tok * 4 + k] = e[k] * inv * Ascale[k];
        dts[tok] = 0.2f * sigm(go[4]);
        gs[tok]  = sigm(q + mb2[0]);
    }
}

// ---------------------------------------------------------------------------
// pack Wu[kr][d] = U[k][d][r], Wv[d][kr] = V[k][r][d]  (both 8192 elems)
__global__ __launch_bounds__(256) void pack_uv_k(const float* __restrict__ U,
                                                 const float* __restrict__ V,
                                                 float* __restrict__ Wu,
                                                 float* __restrict__ Wv)
{
    int i = blockIdx.x * 256 + threadIdx.x;
    if (i < 8192) {
        int kr = i >> 7, d = i & 127;
        int k = kr >> 4, r = kr & 15;
        Wu[i] = U[((size_t)k * DM + d) * RR + r];
        int d2 = i >> 6, kr2 = i & 63;
        int k2 = kr2 >> 4, r2 = kr2 & 15;
        Wv[i] = V[((size_t)k2 * RR + r2) * DM + d2];
    }
}

// ---------------------------------------------------------------------------
// pack Wcat (512x128) = [gw1; mw1; fgw; fbw], bcat(512)
__global__ __launch_bounds__(256) void pack_cat_k(const float* __restrict__ gw1,
                                                  const float* __restrict__ gb1,
                                                  const float* __restrict__ mw1,
                                                  const float* __restrict__ mb1,
                                                  const float* __restrict__ fgw,
                                                  const float* __restrict__ fgb,
                                                  const float* __restrict__ fbw,
                                                  const float* __restrict__ fbb,
                                                  float* __restrict__ Wcat,
                                                  float* __restrict__ bcat)
{
    int i = blockIdx.x * 256 + threadIdx.x;
    if (i < 65536) {
        int r = i >> 7, k = i & 127;
        int sel = r >> 7;
        int rr = r & 127;
        const float* src = (sel == 0) ? gw1 : (sel == 1) ? mw1 : (sel == 2) ? fgw : fbw;
        Wcat[i] = src[rr * DM + k];
    }
    if (i < 512) {
        int sel = i >> 7, rr = i & 127;
        const float* src = (sel == 0) ? gb1 : (sel == 1) ? mb1 : (sel == 2) ? fgb : fbb;
        bcat[i] = src[rr];
    }
}

// ---------------------------------------------------------------------------
// final combine + transpose back to (B,T,N,D); 2 tokens/block
__global__ __launch_bounds__(256) void combine_k(const float* __restrict__ h,
                                                 const float* __restrict__ hA,
                                                 const float* __restrict__ hA2,
                                                 const float* __restrict__ gmb,
                                                 const float* __restrict__ dts,
                                                 const float* __restrict__ gs,
                                                 float* __restrict__ out)
{
    int tid = threadIdx.x;
    int d = tid & 127;
    int tok = blockIdx.x * 2 + (tid >> 7);
    int t = tok & 255;
    int bn = tok >> 8;
    int b = bn >> 5, n = bn & 31;
    float dtv = dts[tok], gv = gs[tok];
    size_t i = (size_t)tok * DM + d;
    float u = tanhf(dtv * hA[i] + 0.5f * dtv * dtv * hA2[i]);
    float gamma = gmb[(size_t)tok * 512 + 256 + d];
    float beta  = gmb[(size_t)tok * 512 + 384 + d];
    u = gamma * u + beta;
    out[(((size_t)b * TT + t) * NN + n) * DM + d] = h[i] + gv * u;
}

// ---------------------------------------------------------------------------
extern "C" void kernel_launch(void* const* d_in, const int* in_sizes, int n_in,
                              void* d_out, int out_size, void* d_ws, size_t ws_size,
                              hipStream_t stream)
{
    const float* x       = (const float*)d_in[0];
    const float* in_w    = (const float*)d_in[1];   // (2,512,128)
    const float* conv_w  = (const float*)d_in[2];   // (2,256,4)
    const float* conv_b  = (const float*)d_in[3];   // (2,256)
    const float* xpw     = (const float*)d_in[4];   // (2,40,256)
    const float* dtw     = (const float*)d_in[5];   // (2,256,8)
    const float* dtb     = (const float*)d_in[6];   // (2,256)
    const float* A_log   = (const float*)d_in[7];   // (2,256,16)
    const float* D_skip  = (const float*)d_in[8];   // (2,256)
    const float* ow      = (const float*)d_in[9];   // (2,128,256)
    const float* U       = (const float*)d_in[10];  // (4,128,16)
    const float* V       = (const float*)d_in[11];  // (4,16,128)
    const float* Ascale  = (const float*)d_in[12];  // (4)
    const float* gw1     = (const float*)d_in[13];
    const float* gb1     = (const float*)d_in[14];
    const float* gw2     = (const float*)d_in[15];
    const float* gb2     = (const float*)d_in[16];
    const float* fgw     = (const float*)d_in[17];
    const float* fgb     = (const float*)d_in[18];
    const float* fbw     = (const float*)d_in[19];
    const float* fbb     = (const float*)d_in[20];
    const float* mw1     = (const float*)d_in[21];
    const float* mb1     = (const float*)d_in[22];
    const float* mw2     = (const float*)d_in[23];
    const float* mb2     = (const float*)d_in[24];

    float* ws = (float*)d_ws;
    float* h    = ws;                       //  4,194,304 floats
    float* xz   = h + 4194304;              // 16,777,216 (final: gmb)
    float* xh   = xz + 16777216;            //  8,388,608 (final: hA, hA2)
    float* xdbl = xh + 8388608;             //  1,310,720 (final: Wcat/bcat/Wu/Wv/ws4/dts/gs)
    // total 30,670,848 floats = 122.7 MB

    pack_h_k<<<TOK / 2, 256, 0, stream>>>(x, h);

    for (int l = 0; l < LL; ++l) {
        const float* iw = in_w + (size_t)l * 512 * 128;
        mgemm_k<0,0><<<dim3(8,256), 256, 0, stream>>>(
            h, DM, iw, nullptr, xz, 512, 512, 128, nullptr, 0);
        conv_silu_k<<<dim3(TT / 4, BN_), 256, 0, stream>>>(
            xz, conv_w + (size_t)l * DI * DCV, conv_b + (size_t)l * DI, xh);
        gemm_k<64,64,4,4,0><<<dim3(1,512), 256, 0, stream>>>(
            xh, DI, xpw + (size_t)l * 40 * DI, nullptr, xdbl, 40, TOK, 40, DI, nullptr);
        scan_k<<<dim3(2, BN_), 512, 0, stream>>>(
            xz, xh, xdbl, dtw + (size_t)l * DI * DTR, dtb + (size_t)l * DI,
            A_log + (size_t)l * DI * SS, D_skip + (size_t)l * DI, xh);
        mgemm_k<4,0><<<dim3(2,256), 256, 0, stream>>>(
            xh, DI, ow + (size_t)l * DM * DI, nullptr, h, DM, 128, 256, nullptr, 0);
    }

    // ---------------- final stage ----------------
    float* gmb  = xz;
    float* Zb   = xz;                       // cols 0..63, stride 512
    float* hA   = xh;
    float* hA2  = xh + 4194304;
    float* Wcat = xdbl;                     // 65,536
    float* bcat = xdbl + 65536;             // 512
    float* Wu   = xdbl + 66048;             // 8,192
    float* Wv   = xdbl + 74240;             // 8,192
    float* ws4  = xdbl + 82432;             // TOK*4
    float* dts  = xdbl + 213504;            // TOK
    float* gs   = xdbl + 246272;            // TOK

    pack_cat_k<<<256, 256, 0, stream>>>(gw1, gb1, mw1, mb1, fgw, fgb, fbw, fbb, Wcat, bcat);
    mgemm_k<1,1><<<dim3(4,256), 256, 0, stream>>>(
        h, DM, Wcat, bcat, gmb, 512, 256, 128, nullptr, 0);
    mgemm_k<1,2><<<dim3(4,256), 256, 0, stream>>>(
        h, DM, Wcat + 256 * 128, bcat + 256, gmb + 256, 512, 256, 128, nullptr, 0);
    gate_k<<<TOK / 4, 256, 0, stream>>>(gmb, gw2, gb2, mw2, mb2, Ascale, ws4, dts, gs);
    pack_uv_k<<<32, 256, 0, stream>>>(U, V, Wu, Wv);

    mgemm_k<6,0><<<dim3(1,256), 256, 0, stream>>>(
        h, DM, Wu, nullptr, Zb, 512, 64, 128, ws4, 0);
    mgemm_k<0,0><<<dim3(2,256), 256, 0, stream>>>(
        Zb, 512, Wv, nullptr, hA, DM, 128, 64, nullptr, 0);
    mgemm_k<6,0><<<dim3(1,256), 256, 0, stream>>>(
        hA, DM, Wu, nullptr, Zb, 512, 64, 128, ws4, 0);
    mgemm_k<0,0><<<dim3(2,256), 256, 0, stream>>>(
        Zb, 512, Wv, nullptr, hA2, DM, 128, 64, nullptr, 0);

    combine_k<<<TOK / 2, 256, 0, stream>>>(h, hA, hA2, gmb, dts, gs, (float*)d_out);
}

// Round 10
// 505.754 us; speedup vs baseline: 2.5179x; 1.0755x over previous
//
#include <hip/hip_runtime.h>
#include <math.h>

// Problem constants
#define BSZ   4
#define TT    256
#define NN    32
#define DM    128
#define LL    2
#define SS    16
#define DCV   4
#define DI    256
#define DTR   8
#define KK    4
#define RR    16
#define BN_   128          // BSZ*NN
#define TOK   32768        // BN_*TT

typedef _Float16 f16x8 __attribute__((ext_vector_type(8)));
typedef float    f32x4 __attribute__((ext_vector_type(4)));

__device__ __forceinline__ float sigm(float x) { return __fdividef(1.f, 1.f + __expf(-x)); }

// ---------------------------------------------------------------------------
// pack x (B,T,N,D) -> h (BN,T,D)
__global__ __launch_bounds__(256) void pack_h_k(const float* __restrict__ x, float* __restrict__ h)
{
    int tid = threadIdx.x;
    int d = tid & 127;
    int tok = blockIdx.x * 2 + (tid >> 7);
    int t = tok & 255;
    int bn = tok >> 8;
    int b = bn >> 5, n = bn & 31;
    h[(size_t)tok * DM + d] = x[(((size_t)b * TT + t) * NN + n) * DM + d];
}

// ---------------------------------------------------------------------------
// MFMA f16 GEMM: C[M,N] = A[M,K] @ W[N,K]^T (+epilogue), fp32 I/O, f16 compute
// Tile 128 (M) x 64 (N), 4 waves, K-chunks of 32, LDS double-buffered.
// EPI: 0 store, 1 +bias(+ACT), 4 C += v, 7 split-store (col<256 -> C ldc256,
//      else C2 ldc256)
// ACT: 0 none, 1 gelu, 2 tanh  (uniform per dispatch)
template<int EPI, int ACT>
__global__ __launch_bounds__(256)
void mgemm_k(const float* __restrict__ A, int lda,
             const float* __restrict__ W,
             const float* __restrict__ bias,
             float* C, float* C2, int ldc,
             int N, int K)
{
    __shared__ char smem[24576];

    const int tid  = threadIdx.x;
    const int lane = tid & 63;
    const int wv   = tid >> 6;            // 0..3
    const long row0 = (long)blockIdx.y * 128;
    const int  colb = blockIdx.x * 64;    // dispatch-local col base
    const int  NC   = K >> 5;             // 32-k chunks

    const int st_rc = tid >> 2;           // 0..63
    const int st_g  = tid & 3;
    const int offA0 = st_rc * 64        + ((st_g ^ (st_rc & 3)) << 4);
    const int offA1 = (st_rc + 64) * 64 + ((st_g ^ (st_rc & 3)) << 4);
    const int offW  = st_rc * 64        + ((st_g ^ (st_rc & 3)) << 4);
    const int wcol  = colb + st_rc;
    const bool wok  = (wcol < N);

    const int fr = lane & 15;
    const int fg = lane >> 4;
    const int ra0 = (wv << 5) + fr;
    const int offa0 = ra0 * 64        + ((fg ^ (ra0 & 3)) << 4);
    const int offa1 = (ra0 + 16) * 64 + ((fg ^ (ra0 & 3)) << 4);
    int offb[4];
#pragma unroll
    for (int nj = 0; nj < 4; ++nj) {
        int cb = (nj << 4) + fr;
        offb[nj] = cb * 64 + ((fg ^ (fr & 3)) << 4);
    }

    f32x4 acc[2][4];
#pragma unroll
    for (int mi = 0; mi < 2; ++mi)
#pragma unroll
        for (int nj = 0; nj < 4; ++nj) acc[mi][nj] = (f32x4){0.f, 0.f, 0.f, 0.f};

    float va0[8], va1[8], vw[8];

    {
        const float* pa0 = A + (row0 + st_rc) * (long)lda + st_g * 8;
        *(float4*)&va0[0] = *(const float4*)pa0;
        *(float4*)&va0[4] = *(const float4*)(pa0 + 4);
        const float* pa1 = pa0 + 64 * (long)lda;
        *(float4*)&va1[0] = *(const float4*)pa1;
        *(float4*)&va1[4] = *(const float4*)(pa1 + 4);
        if (wok) {
            const float* pw = W + (long)wcol * K + st_g * 8;
            *(float4*)&vw[0] = *(const float4*)pw;
            *(float4*)&vw[4] = *(const float4*)(pw + 4);
        } else {
#pragma unroll
            for (int j = 0; j < 8; ++j) vw[j] = 0.f;
        }
    }
    {
        char* base = smem;
        f16x8 h0, h1, hw;
#pragma unroll
        for (int j = 0; j < 8; ++j) { h0[j] = (_Float16)va0[j]; h1[j] = (_Float16)va1[j]; hw[j] = (_Float16)vw[j]; }
        *(f16x8*)(base + offA0) = h0;
        *(f16x8*)(base + offA1) = h1;
        *(f16x8*)(base + 8192 + offW) = hw;
    }
    __syncthreads();

    for (int c = 0; c < NC; ++c) {
        if (c + 1 < NC) {
            const int kk = (c + 1) << 5;
            const float* pa0 = A + (row0 + st_rc) * (long)lda + kk + st_g * 8;
            *(float4*)&va0[0] = *(const float4*)pa0;
            *(float4*)&va0[4] = *(const float4*)(pa0 + 4);
            const float* pa1 = pa0 + 64 * (long)lda;
            *(float4*)&va1[0] = *(const float4*)pa1;
            *(float4*)&va1[4] = *(const float4*)(pa1 + 4);
            if (wok) {
                const float* pw = W + (long)wcol * K + kk + st_g * 8;
                *(float4*)&vw[0] = *(const float4*)pw;
                *(float4*)&vw[4] = *(const float4*)(pw + 4);
            }
        }
        {
            const char* As = smem + (c & 1) * 12288;
            const char* Ws = As + 8192;
            f16x8 af0 = *(const f16x8*)(As + offa0);
            f16x8 af1 = *(const f16x8*)(As + offa1);
            f16x8 bf[4];
#pragma unroll
            for (int nj = 0; nj < 4; ++nj) bf[nj] = *(const f16x8*)(Ws + offb[nj]);
#pragma unroll
            for (int nj = 0; nj < 4; ++nj) {
                acc[0][nj] = __builtin_amdgcn_mfma_f32_16x16x32_f16(af0, bf[nj], acc[0][nj], 0, 0, 0);
                acc[1][nj] = __builtin_amdgcn_mfma_f32_16x16x32_f16(af1, bf[nj], acc[1][nj], 0, 0, 0);
            }
        }
        if (c + 1 < NC) {
            char* base = smem + ((c + 1) & 1) * 12288;
            f16x8 h0, h1, hw;
#pragma unroll
            for (int j = 0; j < 8; ++j) { h0[j] = (_Float16)va0[j]; h1[j] = (_Float16)va1[j]; hw[j] = (_Float16)vw[j]; }
            *(f16x8*)(base + offA0) = h0;
            *(f16x8*)(base + offA1) = h1;
            *(f16x8*)(base + 8192 + offW) = hw;
        }
        __syncthreads();
    }

#pragma unroll
    for (int nj = 0; nj < 4; ++nj) {
        int col = colb + (nj << 4) + fr;
        if (col < N) {
            float bb = 0.f;
            if (EPI == 1 && bias) bb = bias[col];
#pragma unroll
            for (int mi = 0; mi < 2; ++mi) {
                long rg = row0 + (wv << 5) + (mi << 4) + (fg << 2);
#pragma unroll
                for (int r = 0; r < 4; ++r) {
                    float v = acc[mi][nj][r];
                    if (EPI == 1) {
                        v += bb;
                        if (ACT == 1) v = 0.5f * v * (1.f + erff(v * 0.70710678118654752f));
                        else if (ACT == 2) v = tanhf(v);
                    }
                    if (EPI == 7) {
                        float* pc = (col < 256) ? (C + (rg + r) * 256 + col)
                                                : (C2 + (rg + r) * 256 + (col - 256));
                        *pc = v;
                    } else {
                        float* pc = C + (rg + r) * (long)ldc + col;
                        if (EPI == 4) *pc += v;
                        else          *pc = v;
                    }
                }
            }
        }
    }
}

// ---------------------------------------------------------------------------
// fp32 tiled GEMM (kept for the precision-sensitive x_dbl projection)
template<int BM, int BN, int TM, int TN>
__global__ __launch_bounds__(256)
void gemm_k(const float* __restrict__ A, int lda,
            const float* __restrict__ W,
            float* C, int ldc,
            int M, int N, int K)
{
    constexpr int BK = 16;
    constexpr int LDS_A = BM + 4;
    constexpr int LDS_B = BN + 4;
    static_assert((BM / TM) * (BN / TN) == 256, "256 threads");
    constexpr int NA = BM * BK / 1024;
    constexpr int NB = BN * BK / 1024;

    __shared__ float As[BK][LDS_A];
    __shared__ float Ws[BK][LDS_B];

    const int tid = threadIdx.x;
    constexpr int nx = BN / TN;
    const int tx = tid % nx, ty = tid / nx;
    const long row0 = (long)blockIdx.y * BM;
    const long col0 = (long)blockIdx.x * BN;

    float acc[TM][TN];
#pragma unroll
    for (int i = 0; i < TM; i++)
#pragma unroll
        for (int j = 0; j < TN; j++) acc[i][j] = 0.f;

    for (int kk = 0; kk < K; kk += BK) {
        float4 a_reg[NA], w_reg[NB];
#pragma unroll
        for (int i = 0; i < NA; ++i) {
            int idx = i * 1024 + tid * 4;
            int r = idx >> 4, k0 = idx & 15;
            int k = kk + k0;
            const float* p = A + (row0 + r) * (long)lda + k;
            a_reg[i] = *(const float4*)p;
        }
#pragma unroll
        for (int i = 0; i < NB; ++i) {
            int idx = i * 1024 + tid * 4;
            int r = idx >> 4, k0 = idx & 15;
            long gc = col0 + r;
            int k = kk + k0;
            if (gc < N) {
                const float* p = W + gc * (long)K + k;
                w_reg[i] = *(const float4*)p;
            } else w_reg[i] = make_float4(0.f, 0.f, 0.f, 0.f);
        }
        __syncthreads();
#pragma unroll
        for (int i = 0; i < NA; ++i) {
            int idx = i * 1024 + tid * 4;
            int r = idx >> 4, k0 = idx & 15;
            As[k0 + 0][r] = a_reg[i].x; As[k0 + 1][r] = a_reg[i].y;
            As[k0 + 2][r] = a_reg[i].z; As[k0 + 3][r] = a_reg[i].w;
        }
#pragma unroll
        for (int i = 0; i < NB; ++i) {
            int idx = i * 1024 + tid * 4;
            int r = idx >> 4, k0 = idx & 15;
            Ws[k0 + 0][r] = w_reg[i].x; Ws[k0 + 1][r] = w_reg[i].y;
            Ws[k0 + 2][r] = w_reg[i].z; Ws[k0 + 3][r] = w_reg[i].w;
        }
        __syncthreads();
#pragma unroll
        for (int k = 0; k < BK; ++k) {
            float a_f[TM], w_f[TN];
#pragma unroll
            for (int i = 0; i < TM; i += 4)
                *(float4*)&a_f[i] = *(const float4*)&As[k][ty * TM + i];
#pragma unroll
            for (int j = 0; j < TN; j += 4)
                *(float4*)&w_f[j] = *(const float4*)&Ws[k][tx * TN + j];
#pragma unroll
            for (int i = 0; i < TM; i++)
#pragma unroll
                for (int j = 0; j < TN; j++)
                    acc[i][j] = fmaf(a_f[i], w_f[j], acc[i][j]);
        }
    }
#pragma unroll
    for (int i = 0; i < TM; i++) {
        long r = row0 + ty * TM + i;
#pragma unroll
        for (int j = 0; j < TN; j++) {
            long c = col0 + tx * TN + j;
            if (c < N) C[r * ldc + c] = acc[i][j];
        }
    }
}

// ---------------------------------------------------------------------------
// causal depthwise conv (DC=4) + SiLU; 4 t per thread; dense xhalf input.
__global__ __launch_bounds__(256) void conv_silu_k(const float* __restrict__ xhalf,
                                                   const float* __restrict__ cw,
                                                   const float* __restrict__ cb,
                                                   float* __restrict__ xh)
{
    int c = threadIdx.x;       // 0..255
    int t0 = blockIdx.x << 2;  // 0,4,..252
    int bn = blockIdx.y;       // 0..127
    float w0 = cw[c * 4 + 0], w1 = cw[c * 4 + 1], w2 = cw[c * 4 + 2], w3 = cw[c * 4 + 3];
    float bb = cb[c];
    size_t base = ((size_t)bn * TT + t0) * DI + c;
    float xm3 = (t0 >= 3) ? xhalf[base - 3 * DI] : 0.f;
    float xm2 = (t0 >= 2) ? xhalf[base - 2 * DI] : 0.f;
    float xm1 = (t0 >= 1) ? xhalf[base - DI]     : 0.f;
    float x0 = xhalf[base];
    float x1 = xhalf[base + DI];
    float x2 = xhalf[base + 2 * DI];
    float x3 = xhalf[base + 3 * DI];
    float o0 = bb + w3 * x0 + w2 * xm1 + w1 * xm2 + w0 * xm3;
    float o1 = bb + w3 * x1 + w2 * x0  + w1 * xm1 + w0 * xm2;
    float o2 = bb + w3 * x2 + w2 * x1  + w1 * x0  + w0 * xm1;
    float o3 = bb + w3 * x3 + w2 * x2  + w1 * x1  + w0 * x0;
    size_t ob = base;
    xh[ob]           = o0 * sigm(o0);
    xh[ob + DI]      = o1 * sigm(o1);
    xh[ob + 2 * DI]  = o2 * sigm(o2);
    xh[ob + 3 * DI]  = o3 * sigm(o3);
}

// ---------------------------------------------------------------------------
// selective scan v4: 4 states/thread, 512 threads (8 waves), dt fused in,
// silu(z) hoisted to staging (once per (t,d), not x4 per s-quad).
#define SCH 16
__global__ __launch_bounds__(512) void scan_k(const float* __restrict__ zbuf,
                                              const float* xhp,         // aliases yg
                                              const float* __restrict__ xdbl,
                                              const float* __restrict__ dtw,
                                              const float* __restrict__ dtb,
                                              const float* __restrict__ A_log,
                                              const float* __restrict__ Dp,
                                              float* yg)
{
    __shared__ float sdt[2][SCH][128];
    __shared__ float sxv[2][SCH][128];
    __shared__ float szz[2][SCH][128];
    __shared__ float sbc[2][SCH][32];
    __shared__ float sxd[2][SCH][8];

    const int tid  = threadIdx.x;         // 0..511
    const int lane = tid & 63;
    const int wave = tid >> 6;            // 0..7
    const int sq   = lane >> 4;           // 0..3 (s-quad)
    const int dloc = (wave << 4) + (lane & 15);   // 0..127
    const int bn   = blockIdx.y;
    const int dbase= blockIdx.x << 7;
    const int d    = dbase + dloc;
    const size_t tokb = (size_t)bn * TT;

    float A[4];
#pragma unroll
    for (int q = 0; q < 4; ++q)
        A[q] = -__expf(A_log[d * SS + sq * 4 + q]);
    const float Dv = Dp[d];

    float st[4];
#pragma unroll
    for (int q = 0; q < 4; ++q) st[q] = 0.f;

    // --- staging roles ---
    const int st0 = tid >> 5;                   // 0..15 (step row)
    const int sc0 = (tid & 31) << 2;            // 0..124 (d col, float4)
    const int bstep = tid >> 3, bq = (tid & 7) << 2;   // B/C (tid<128)
    const int xi = tid - 128;                   // xdbl dt-cols (tid 128..159)
    const int xr = xi >> 1, xc4 = (xi & 1) << 2;
    float4 rxv, rzz, rbc, rxd;

    // --- dt compute role: s = tid>>5, 4 consecutive d ---
    const int dt_s  = tid >> 5;                 // 0..15
    const int dt_d4 = (tid & 31) << 2;          // 0..124
    float dtwv[4][8];
    float dtbv[4];
#pragma unroll
    for (int j = 0; j < 4; ++j) {
        const float* p = dtw + (size_t)(dbase + dt_d4 + j) * 8;
        *(float4*)&dtwv[j][0] = *(const float4*)p;
        *(float4*)&dtwv[j][4] = *(const float4*)(p + 4);
        dtbv[j] = dtb[dbase + dt_d4 + j];
    }

#define STAGE_ISSUE(TB) do {                                              \
    size_t tb_ = tokb + (TB);                                             \
    rxv = *(const float4*)&xhp [(tb_ + st0) * DI + dbase + sc0];          \
    rzz = *(const float4*)&zbuf[(tb_ + st0) * DI + dbase + sc0];          \
    if (tid < 128) rbc = *(const float4*)&xdbl[(tb_ + bstep) * 40 + 8 + bq]; \
    else if (tid < 160) rxd = *(const float4*)&xdbl[(tb_ + xr) * 40 + xc4]; \
} while (0)

#define STAGE_WRITE(B) do {                                               \
    *(float4*)&sxv[B][st0][sc0] = rxv;                                    \
    float4 zs_;                                                           \
    zs_.x = rzz.x * sigm(rzz.x); zs_.y = rzz.y * sigm(rzz.y);             \
    zs_.z = rzz.z * sigm(rzz.z); zs_.w = rzz.w * sigm(rzz.w);             \
    *(float4*)&szz[B][st0][sc0] = zs_;                                    \
    if (tid < 128) *(float4*)&sbc[B][bstep][bq] = rbc;                    \
    else if (tid < 160) *(float4*)&sxd[B][xr][xc4] = rxd;                 \
} while (0)

#define DT_COMPUTE(B) do {                                                \
    float4 o_;                                                            \
    _Pragma("unroll")                                                     \
    for (int j = 0; j < 4; ++j) {                                         \
        float v_ = dtbv[j];                                               \
        _Pragma("unroll")                                                 \
        for (int k = 0; k < 8; ++k)                                       \
            v_ = fmaf(sxd[B][dt_s][k], dtwv[j][k], v_);                   \
        o_[j] = fmaxf(v_, 0.f) + __logf(1.f + __expf(-fabsf(v_)));        \
    }                                                                     \
    *(float4*)&sdt[B][dt_s][dt_d4] = o_;                                  \
} while (0)

    STAGE_ISSUE(0);
    STAGE_WRITE(0);
    __syncthreads();
    DT_COMPUTE(0);
    __syncthreads();

    for (int c = 0; c < TT / SCH; ++c) {
        const int b = c & 1;
        const bool more = (c + 1 < TT / SCH);
        if (more) STAGE_ISSUE((c + 1) * SCH);
        const int tb = c * SCH;
#pragma unroll
        for (int s = 0; s < SCH; ++s) {
            float dt_c = sdt[b][s][dloc];
            float xv_c = sxv[b][s][dloc];
            float zg   = szz[b][s][dloc];
            float4 B4 = *(const float4*)&sbc[b][s][sq << 2];
            float4 C4 = *(const float4*)&sbc[b][s][16 + (sq << 2)];

            float dtx = dt_c * xv_c;
            float dA0 = __expf(A[0] * dt_c);
            float dA1 = __expf(A[1] * dt_c);
            float dA2 = __expf(A[2] * dt_c);
            float dA3 = __expf(A[3] * dt_c);
            st[0] = fmaf(dA0, st[0], dtx * B4.x);
            st[1] = fmaf(dA1, st[1], dtx * B4.y);
            st[2] = fmaf(dA2, st[2], dtx * B4.z);
            st[3] = fmaf(dA3, st[3], dtx * B4.w);
            float y0 = st[0] * C4.x;
            float y1 = st[1] * C4.y;
            y0 = fmaf(st[2], C4.z, y0);
            y1 = fmaf(st[3], C4.w, y1);
            float y = y0 + y1;
            y += __shfl_xor(y, 16, 64);
            y += __shfl_xor(y, 32, 64);
            float outv = (y + Dv * xv_c) * zg;
            if (sq == 0) yg[(tokb + tb + s) * DI + d] = outv;
        }
        if (more) STAGE_WRITE(b ^ 1);
        __syncthreads();
        if (more) DT_COMPUTE(b ^ 1);
        __syncthreads();
    }
#undef STAGE_ISSUE
#undef STAGE_WRITE
#undef DT_COMPUTE
}

// ---------------------------------------------------------------------------
// per-token small projections on fused buffer (stride 512); 4 tokens/block
__global__ __launch_bounds__(256) void gate_k(const float* __restrict__ gmb,
                                              const float* __restrict__ gw2,
                                              const float* __restrict__ gb2,
                                              const float* __restrict__ mw2,
                                              const float* __restrict__ mb2,
                                              const float* __restrict__ Ascale,
                                              float* __restrict__ ws4,
                                              float* __restrict__ dts,
                                              float* __restrict__ gs)
{
    int l = threadIdx.x & 63;
    int tok = blockIdx.x * 4 + (threadIdx.x >> 6);
    const float* g1 = gmb + (size_t)tok * 512;
    float a0 = g1[l], a1 = g1[l + 64];
    float m0 = g1[128 + l], m1v = g1[192 + l];
    float p[5];
#pragma unroll
    for (int j = 0; j < 5; j++)
        p[j] = a0 * gw2[j * DM + l] + a1 * gw2[j * DM + l + 64];
    float q = m0 * mw2[l] + m1v * mw2[l + 64];
#pragma unroll
    for (int off = 32; off; off >>= 1) {
#pragma unroll
        for (int j = 0; j < 5; j++) p[j] += __shfl_xor(p[j], off, 64);
        q += __shfl_xor(q, off, 64);
    }
    if (l == 0) {
        float go[5];
#pragma unroll
        for (int j = 0; j < 5; j++) go[j] = p[j] + gb2[j];
        float mx = fmaxf(fmaxf(go[0], go[1]), fmaxf(go[2], go[3]));
        float e[4], sum = 0.f;
#pragma unroll
        for (int k = 0; k < 4; k++) { e[k] = expf(go[k] - mx); sum += e[k]; }
        float inv = 1.f / sum;
#pragma unroll
        for (int k = 0; k < 4; k++) ws4[(size_t)tok * 4 + k] = e[k] * inv * Ascale[k];
        dts[tok] = 0.2f * sigm(go[4]);
        gs[tok]  = sigm(q + mb2[0]);
    }
}

// ---------------------------------------------------------------------------
// pack Wu[kr][d] = U[k][d][r], Wv[d][kr] = V[k][r][d]  (both 8192 elems)
__global__ __launch_bounds__(256) void pack_uv_k(const float* __restrict__ U,
                                                 const float* __restrict__ V,
                                                 float* __restrict__ Wu,
                                                 float* __restrict__ Wv)
{
    int i = blockIdx.x * 256 + threadIdx.x;
    if (i < 8192) {
        int kr = i >> 7, d = i & 127;
        int k = kr >> 4, r = kr & 15;
        Wu[i] = U[((size_t)k * DM + d) * RR + r];
        int d2 = i >> 6, kr2 = i & 63;
        int k2 = kr2 >> 4, r2 = kr2 & 15;
        Wv[i] = V[((size_t)k2 * RR + r2) * DM + d2];
    }
}

// ---------------------------------------------------------------------------
// pack Wcat (512x128) = [gw1; mw1; fgw; fbw], bcat(512)
__global__ __launch_bounds__(256) void pack_cat_k(const float* __restrict__ gw1,
                                                  const float* __restrict__ gb1,
                                                  const float* __restrict__ mw1,
                                                  const float* __restrict__ mb1,
                                                  const float* __restrict__ fgw,
                                                  const float* __restrict__ fgb,
                                                  const float* __restrict__ fbw,
                                                  const float* __restrict__ fbb,
                                                  float* __restrict__ Wcat,
                                                  float* __restrict__ bcat)
{
    int i = blockIdx.x * 256 + threadIdx.x;
    if (i < 65536) {
        int r = i >> 7, k = i & 127;
        int sel = r >> 7;
        int rr = r & 127;
        const float* src = (sel == 0) ? gw1 : (sel == 1) ? mw1 : (sel == 2) ? fgw : fbw;
        Wcat[i] = src[rr * DM + k];
    }
    if (i < 512) {
        int sel = i >> 7, rr = i & 127;
        const float* src = (sel == 0) ? gb1 : (sel == 1) ? mb1 : (sel == 2) ? fgb : fbb;
        bcat[i] = src[rr];
    }
}

// ---------------------------------------------------------------------------
// Fused amix x2 + FiLM + gate + residual + transpose-out.
// Per block: 128 tokens. All 4 low-rank GEMM passes through LDS; hA/hA2 kept
// in f32 registers; epilogue does tanh-FiLM-gate and scattered store.
__global__ __launch_bounds__(256) void amix_combine_k(
    const float* __restrict__ h,     // TOK x 128
    const float* __restrict__ Wu,    // 64 x 128  (row kr, col d)
    const float* __restrict__ Wv,    // 128 x 64  (row d, col kr)
    const float* __restrict__ ws4,   // TOK x 4
    const float* __restrict__ gmb,   // TOK x 512 (gamma @256, beta @384)
    const float* __restrict__ dts,
    const float* __restrict__ gs,
    float* __restrict__ out)
{
    __shared__ char smem[81920];
    char* At  = smem;            // 32768: A tile 128r x 128k (4 chunks x 8KB)
    char* Wus = smem + 32768;    // 16384: Wu 64c x 128k (4 chunks x 4KB)
    char* Zt  = smem + 49152;    // 16384: Z 128r x 64k (2 chunks x 8KB)
    char* Wvs = smem + 65536;    // 16384: Wv 128c x 64k (2 chunks x 8KB)

    const int tid  = threadIdx.x;
    const int lane = tid & 63;
    const int wv   = tid >> 6;
    const long r0  = (long)blockIdx.x * 128;
    const int fr = lane & 15;
    const int fg = lane >> 4;

    // ---- stage h (f32->f16, swizzled chunk-major) ----
#pragma unroll
    for (int i = 0; i < 8; ++i) {
        int idx = i * 256 + tid;
        int row = idx >> 4, gk = idx & 15;
        int c = gk >> 2, g = gk & 3;
        const float* p = h + (r0 + row) * 128 + gk * 8;
        float4 v0 = *(const float4*)p, v1 = *(const float4*)(p + 4);
        f16x8 hv;
        hv[0] = (_Float16)v0.x; hv[1] = (_Float16)v0.y; hv[2] = (_Float16)v0.z; hv[3] = (_Float16)v0.w;
        hv[4] = (_Float16)v1.x; hv[5] = (_Float16)v1.y; hv[6] = (_Float16)v1.z; hv[7] = (_Float16)v1.w;
        *(f16x8*)(At + c * 8192 + row * 64 + ((g ^ (row & 3)) << 4)) = hv;
    }
    // ---- stage Wu ----
#pragma unroll
    for (int i = 0; i < 4; ++i) {
        int idx = i * 256 + tid;
        int col = idx >> 4, gk = idx & 15;
        int c = gk >> 2, g = gk & 3;
        const float* p = Wu + col * 128 + gk * 8;
        float4 v0 = *(const float4*)p, v1 = *(const float4*)(p + 4);
        f16x8 hv;
        hv[0] = (_Float16)v0.x; hv[1] = (_Float16)v0.y; hv[2] = (_Float16)v0.z; hv[3] = (_Float16)v0.w;
        hv[4] = (_Float16)v1.x; hv[5] = (_Float16)v1.y; hv[6] = (_Float16)v1.z; hv[7] = (_Float16)v1.w;
        *(f16x8*)(Wus + c * 4096 + col * 64 + ((g ^ (col & 3)) << 4)) = hv;
    }
    // ---- stage Wv ----
#pragma unroll
    for (int i = 0; i < 4; ++i) {
        int idx = i * 256 + tid;
        int col = idx >> 3, gk = idx & 7;
        int c = gk >> 2, g = gk & 3;
        const float* p = Wv + col * 64 + gk * 8;
        float4 v0 = *(const float4*)p, v1 = *(const float4*)(p + 4);
        f16x8 hv;
        hv[0] = (_Float16)v0.x; hv[1] = (_Float16)v0.y; hv[2] = (_Float16)v0.z; hv[3] = (_Float16)v0.w;
        hv[4] = (_Float16)v1.x; hv[5] = (_Float16)v1.y; hv[6] = (_Float16)v1.z; hv[7] = (_Float16)v1.w;
        *(f16x8*)(Wvs + c * 8192 + col * 64 + ((g ^ (col & 3)) << 4)) = hv;
    }
    __syncthreads();

    const int ra0 = (wv << 5) + fr;
    const int ra1 = ra0 + 16;
    const int offa0 = ra0 * 64 + ((fg ^ (ra0 & 3)) << 4);
    const int offa1 = ra1 * 64 + ((fg ^ (ra1 & 3)) << 4);
    int offbu[4];
#pragma unroll
    for (int nj = 0; nj < 4; ++nj) {
        int cb = (nj << 4) + fr;
        offbu[nj] = cb * 64 + ((fg ^ (fr & 3)) << 4);
    }
    int offbv[8];
#pragma unroll
    for (int nj = 0; nj < 8; ++nj) {
        int cb = (nj << 4) + fr;
        offbv[nj] = cb * 64 + ((fg ^ (fr & 3)) << 4);
    }

#define ZPASS(SRC, ACCZ) do {                                              \
    _Pragma("unroll")                                                      \
    for (int c = 0; c < 4; ++c) {                                          \
        f16x8 a0 = *(const f16x8*)(SRC + c * 8192 + offa0);                \
        f16x8 a1 = *(const f16x8*)(SRC + c * 8192 + offa1);                \
        _Pragma("unroll")                                                  \
        for (int nj = 0; nj < 4; ++nj) {                                   \
            f16x8 bf = *(const f16x8*)(Wus + c * 4096 + offbu[nj]);        \
            ACCZ[0][nj] = __builtin_amdgcn_mfma_f32_16x16x32_f16(a0, bf, ACCZ[0][nj], 0, 0, 0); \
            ACCZ[1][nj] = __builtin_amdgcn_mfma_f32_16x16x32_f16(a1, bf, ACCZ[1][nj], 0, 0, 0); \
        }                                                                  \
    }                                                                      \
} while (0)

#define ZSCALE_STORE(ACCZ) do {                                            \
    _Pragma("unroll")                                                      \
    for (int mi = 0; mi < 2; ++mi) {                                       \
        _Pragma("unroll")                                                  \
        for (int r = 0; r < 4; ++r) {                                      \
            int row = (wv << 5) + (mi << 4) + (fg << 2) + r;               \
            const float* wp = ws4 + (r0 + row) * 4;                        \
            _Pragma("unroll")                                              \
            for (int nj = 0; nj < 4; ++nj) {                               \
                float v = ACCZ[mi][nj][r] * wp[nj];                        \
                int col = (nj << 4) + fr;                                  \
                int c2 = col >> 5, g2 = (col >> 3) & 3, e2 = col & 7;      \
                *(_Float16*)(Zt + c2 * 8192 + row * 64 +                   \
                    ((g2 ^ (row & 3)) << 4) + e2 * 2) = (_Float16)v;       \
            }                                                              \
        }                                                                  \
    }                                                                      \
} while (0)

#define VPASS(ACCV) do {                                                   \
    _Pragma("unroll")                                                      \
    for (int c = 0; c < 2; ++c) {                                          \
        f16x8 a0 = *(const f16x8*)(Zt + c * 8192 + offa0);                 \
        f16x8 a1 = *(const f16x8*)(Zt + c * 8192 + offa1);                 \
        _Pragma("unroll")                                                  \
        for (int nj = 0; nj < 8; ++nj) {                                   \
            f16x8 bf = *(const f16x8*)(Wvs + c * 8192 + offbv[nj]);        \
            ACCV[0][nj] = __builtin_amdgcn_mfma_f32_16x16x32_f16(a0, bf, ACCV[0][nj], 0, 0, 0); \
            ACCV[1][nj] = __builtin_amdgcn_mfma_f32_16x16x32_f16(a1, bf, ACCV[1][nj], 0, 0, 0); \
        }                                                                  \
    }                                                                      \
} while (0)

    // pass 1: Z = (h @ Wu^T) * w
    f32x4 accZ[2][4];
#pragma unroll
    for (int mi = 0; mi < 2; ++mi)
#pragma unroll
        for (int nj = 0; nj < 4; ++nj) accZ[mi][nj] = (f32x4){0.f, 0.f, 0.f, 0.f};
    ZPASS(At, accZ);
    ZSCALE_STORE(accZ);
    __syncthreads();

    // pass 2: hA = Z @ Wv^T  (keep in regs)
    f32x4 accA[2][8];
#pragma unroll
    for (int mi = 0; mi < 2; ++mi)
#pragma unroll
        for (int nj = 0; nj < 8; ++nj) accA[mi][nj] = (f32x4){0.f, 0.f, 0.f, 0.f};
    VPASS(accA);
    // write hA (f16) over At for pass 3
#pragma unroll
    for (int mi = 0; mi < 2; ++mi)
#pragma unroll
        for (int nj = 0; nj < 8; ++nj)
#pragma unroll
            for (int r = 0; r < 4; ++r) {
                int row = (wv << 5) + (mi << 4) + (fg << 2) + r;
                int col = (nj << 4) + fr;
                int c3 = col >> 5, g3 = (col >> 3) & 3, e3 = col & 7;
                *(_Float16*)(At + c3 * 8192 + row * 64 +
                    ((g3 ^ (row & 3)) << 4) + e3 * 2) = (_Float16)accA[mi][nj][r];
            }
    __syncthreads();

    // pass 3: Z2 = (hA @ Wu^T) * w
#pragma unroll
    for (int mi = 0; mi < 2; ++mi)
#pragma unroll
        for (int nj = 0; nj < 4; ++nj) accZ[mi][nj] = (f32x4){0.f, 0.f, 0.f, 0.f};
    ZPASS(At, accZ);
    ZSCALE_STORE(accZ);
    __syncthreads();

    // pass 4: hA2 = Z2 @ Wv^T
    f32x4 accB[2][8];
#pragma unroll
    for (int mi = 0; mi < 2; ++mi)
#pragma unroll
        for (int nj = 0; nj < 8; ++nj) accB[mi][nj] = (f32x4){0.f, 0.f, 0.f, 0.f};
    VPASS(accB);

    // ---- epilogue: u = tanh(dt*hA + .5dt^2*hA2); FiLM; gate; residual; store
#pragma unroll
    for (int mi = 0; mi < 2; ++mi) {
#pragma unroll
        for (int r = 0; r < 4; ++r) {
            int row = (wv << 5) + (mi << 4) + (fg << 2) + r;
            long tok = r0 + row;
            float dtv = dts[tok], gv = gs[tok];
            float hdt = 0.5f * dtv * dtv;
            int t = (int)(tok & 255);
            int bn = (int)(tok >> 8);
            int b = bn >> 5, n = bn & 31;
            float* orow = out + (((size_t)b * TT + t) * NN + n) * DM;
            const float* hrow = h + tok * 128;
            const float* grow = gmb + tok * 512;
#pragma unroll
            for (int nj = 0; nj < 8; ++nj) {
                int col = (nj << 4) + fr;
                float u = tanhf(dtv * accA[mi][nj][r] + hdt * accB[mi][nj][r]);
                float gam = grow[256 + col];
                float bet = grow[384 + col];
                u = gam * u + bet;
                orow[col] = hrow[col] + gv * u;
            }
        }
    }
#undef ZPASS
#undef ZSCALE_STORE
#undef VPASS
}

// ---------------------------------------------------------------------------
extern "C" void kernel_launch(void* const* d_in, const int* in_sizes, int n_in,
                              void* d_out, int out_size, void* d_ws, size_t ws_size,
                              hipStream_t stream)
{
    const float* x       = (const float*)d_in[0];
    const float* in_w    = (const float*)d_in[1];   // (2,512,128)
    const float* conv_w  = (const float*)d_in[2];   // (2,256,4)
    const float* conv_b  = (const float*)d_in[3];   // (2,256)
    const float* xpw     = (const float*)d_in[4];   // (2,40,256)
    const float* dtw     = (const float*)d_in[5];   // (2,256,8)
    const float* dtb     = (const float*)d_in[6];   // (2,256)
    const float* A_log   = (const float*)d_in[7];   // (2,256,16)
    const float* D_skip  = (const float*)d_in[8];   // (2,256)
    const float* ow      = (const float*)d_in[9];   // (2,128,256)
    const float* U       = (const float*)d_in[10];  // (4,128,16)
    const float* V       = (const float*)d_in[11];  // (4,16,128)
    const float* Ascale  = (const float*)d_in[12];  // (4)
    const float* gw1     = (const float*)d_in[13];
    const float* gb1     = (const float*)d_in[14];
    const float* gw2     = (const float*)d_in[15];
    const float* gb2     = (const float*)d_in[16];
    const float* fgw     = (const float*)d_in[17];
    const float* fgb     = (const float*)d_in[18];
    const float* fbw     = (const float*)d_in[19];
    const float* fbb     = (const float*)d_in[20];
    const float* mw1     = (const float*)d_in[21];
    const float* mb1     = (const float*)d_in[22];
    const float* mw2     = (const float*)d_in[23];
    const float* mb2     = (const float*)d_in[24];

    float* ws = (float*)d_ws;
    float* h     = ws;                      //  4,194,304 floats
    float* xz    = h + 4194304;             // 16,777,216: xhalf | zbuf; final: gmb
    float* xhalf = xz;                      //  TOK*256
    float* zbuf  = xz + 8388608;            //  TOK*256
    float* xh    = xz + 16777216;           //  8,388,608 (conv out / yg)
    float* xdbl  = xh + 8388608;            //  1,310,720 (final: Wcat etc.)
    // total 30,670,848 floats = 122.7 MB

    pack_h_k<<<TOK / 2, 256, 0, stream>>>(x, h);

    for (int l = 0; l < LL; ++l) {
        const float* iw = in_w + (size_t)l * 512 * 128;
        // in_proj: split-store x-half -> xhalf (dense), z-half -> zbuf (dense)
        mgemm_k<7,0><<<dim3(8,256), 256, 0, stream>>>(
            h, DM, iw, nullptr, xhalf, zbuf, 0, 512, 128);
        conv_silu_k<<<dim3(TT / 4, BN_), 256, 0, stream>>>(
            xhalf, conv_w + (size_t)l * DI * DCV, conv_b + (size_t)l * DI, xh);
        gemm_k<64,64,4,4><<<dim3(1,512), 256, 0, stream>>>(
            xh, DI, xpw + (size_t)l * 40 * DI, xdbl, 40, TOK, 40, DI);
        scan_k<<<dim3(2, BN_), 512, 0, stream>>>(
            zbuf, xh, xdbl, dtw + (size_t)l * DI * DTR, dtb + (size_t)l * DI,
            A_log + (size_t)l * DI * SS, D_skip + (size_t)l * DI, xh);
        mgemm_k<4,0><<<dim3(2,256), 256, 0, stream>>>(
            xh, DI, ow + (size_t)l * DM * DI, nullptr, h, nullptr, DM, 128, 256);
    }

    // ---------------- final stage ----------------
    float* gmb  = xz;                       // TOK x 512
    float* Wcat = xdbl;                     // 65,536
    float* bcat = xdbl + 65536;             // 512
    float* Wu   = xdbl + 66048;             // 8,192
    float* Wv   = xdbl + 74240;             // 8,192
    float* ws4  = xdbl + 82432;             // TOK*4
    float* dts  = xdbl + 213504;            // TOK
    float* gs   = xdbl + 246272;            // TOK

    pack_cat_k<<<256, 256, 0, stream>>>(gw1, gb1, mw1, mb1, fgw, fgb, fbw, fbb, Wcat, bcat);
    mgemm_k<1,1><<<dim3(4,256), 256, 0, stream>>>(
        h, DM, Wcat, bcat, gmb, nullptr, 512, 256, 128);
    mgemm_k<1,2><<<dim3(4,256), 256, 0, stream>>>(
        h, DM, Wcat + 256 * 128, bcat + 256, gmb + 256, nullptr, 512, 256, 128);
    gate_k<<<TOK / 4, 256, 0, stream>>>(gmb, gw2, gb2, mw2, mb2, Ascale, ws4, dts, gs);
    pack_uv_k<<<32, 256, 0, stream>>>(U, V, Wu, Wv);

    amix_combine_k<<<TOK / 128, 256, 0, stream>>>(
        h, Wu, Wv, ws4, gmb, dts, gs, (float*)d_out);
}